// Round 14
// baseline (1007.716 us; speedup 1.0000x reference)
//
#include <hip/hip_runtime.h>
#include <hip/hip_bf16.h>

typedef __hip_bfloat16 bf16;
typedef __attribute__((ext_vector_type(8))) short bf16x8;
typedef __attribute__((ext_vector_type(4))) float f32x4;

#define HIDDEN 128
#define NNODES 50000
#define NEDGES 800000

static __device__ __forceinline__ float b2f(bf16 v) { return __bfloat162float(v); }
static __device__ __forceinline__ short f2bs(float f) {
    bf16 b = __float2bfloat16(f);
    return *reinterpret_cast<const short*>(&b);
}
static __device__ __forceinline__ float bs2f(short s) {
    unsigned x = ((unsigned)(unsigned short)s) << 16;
    return *reinterpret_cast<const float*>(&x);
}
static __device__ __forceinline__ bf16x8 ld_frag(const bf16* p) {
    return *reinterpret_cast<const bf16x8*>(p);
}
static __device__ __forceinline__ bf16x8 zero8() {
    bf16x8 z = {0, 0, 0, 0, 0, 0, 0, 0};
    return z;
}
static __device__ __forceinline__ float u2f_lo(unsigned u) {
    unsigned x = u << 16; return *reinterpret_cast<const float*>(&x);
}
static __device__ __forceinline__ float u2f_hi(unsigned u) {
    unsigned x = u & 0xffff0000u; return *reinterpret_cast<const float*>(&x);
}
static __device__ __forceinline__ bf16x8 ld_a8(const void* base, size_t off, bool f32) {
    if (!f32) return *reinterpret_cast<const bf16x8*>((const bf16*)base + off);
    const float4* p = reinterpret_cast<const float4*>((const float*)base + off);
    float4 u = p[0], w = p[1];
    bf16x8 r;
    r[0]=f2bs(u.x); r[1]=f2bs(u.y); r[2]=f2bs(u.z); r[3]=f2bs(u.w);
    r[4]=f2bs(w.x); r[5]=f2bs(w.y); r[6]=f2bs(w.z); r[7]=f2bs(w.w);
    return r;
}
static __device__ __forceinline__ float gelu_ex(float v) {
    return 0.5f * v * (1.f + erff(v * 0.70710678118654752f));
}

#define C_EMB_B   0
#define C_EMB_G   128
#define C_EMB_BT  256
#define C_EPS     384
#define C_LIN_B   400
#define C_B1      800
#define C_G1      1568
#define C_BT1     2336
#define C_B2      3104
#define C_G2      3488
#define C_BT2     3872

__global__ void k_init(float* __restrict__ stats, int* __restrict__ cursorA,
                       int* __restrict__ cursorB, int doSort) {
    int tid = blockIdx.x * 256 + threadIdx.x;
    int stride = gridDim.x * 256;
    for (int i = tid; i < 3584; i += stride) stats[i] = 0.f;
    if (doSort) for (int i = tid; i < NNODES; i += stride) cursorA[i] = 0;
    for (int i = tid; i < NNODES; i += stride) cursorB[i] = 0;
}

__global__ void k_detect_cvt(const unsigned* __restrict__ gones,
                             const unsigned* __restrict__ eiw, int* __restrict__ flags,
                             const void* emb_b, const void* emb_g, const void* emb_bt,
                             const void* eps, const void* lin_b, const void* b1,
                             const void* g1, const void* bt1, const void* b2,
                             const void* g2, const void* bt2, bf16* __restrict__ canon) {
    __shared__ int sf;
    if (threadIdx.x == 0) {
        int f0 = (gones[0] == 0x3F803F80u) ? 1 : 0;
        unsigned s = 0;
        for (int i = 1; i < 64; i += 2) s |= eiw[i];
        flags[0] = f0; flags[1] = (s == 0u) ? 1 : 0;
        sf = f0;
    }
    __syncthreads();
    bool f32 = (sf == 0);
    const void* ps[11] = {emb_b, emb_g, emb_bt, eps, lin_b, b1, g1, bt1, b2, g2, bt2};
    const int   ns[11] = {128, 128, 128, 3, 384, 768, 768, 768, 384, 384, 384};
    const int   os[11] = {C_EMB_B, C_EMB_G, C_EMB_BT, C_EPS, C_LIN_B, C_B1,
                          C_G1, C_BT1, C_B2, C_G2, C_BT2};
    for (int seg = 0; seg < 11; ++seg)
        for (int i = threadIdx.x; i < ns[seg]; i += 256) {
            short v = f32 ? f2bs(((const float*)ps[seg])[i]) : ((const short*)ps[seg])[i];
            ((short*)canon)[os[seg] + i] = v;
        }
}

__global__ void k_repack_all(const void* __restrict__ emb_w, const void* __restrict__ lin_w,
                             const void* __restrict__ w1, const void* __restrict__ w2,
                             bf16* __restrict__ Wf, const int* __restrict__ flags) {
    const int starts[11] = {0, 16384, 24576, 32768, 40960, 73728, 106496,
                            139264, 172032, 204800, 237568};
    int idx = blockIdx.x * 256 + threadIdx.x;
    if (idx >= 237568) return;
    bool f32 = (flags[0] == 0);
    int seg = 0;
    while (idx >= starts[seg + 1]) ++seg;
    int local = idx - starts[seg];
    const void* base; long long eoff; int K, N;
    if (seg == 0)      { base = emb_w; eoff = 0;                          K = 128; N = 128; }
    else if (seg <= 3) { base = lin_w; eoff = (long long)(seg - 1) * 8192;  K = 64;  N = 128; }
    else if (seg <= 6) { base = w1;    eoff = (long long)(seg - 4) * 32768; K = 128; N = 256; }
    else               { base = w2;    eoff = (long long)(seg - 7) * 32768; K = 256; N = 128; }
    int j    = local & 7;
    int lane = (local >> 3) & 63;
    int rest = local >> 9;
    int NF   = N >> 4;
    int ks   = rest / NF;
    int nf   = rest - ks * NF;
    int k = ks * 32 + ((lane >> 4) << 3) + j;
    int n = (nf << 4) + (lane & 15);
    long long src = eoff + (long long)k * N + n;
    short v = f32 ? f2bs(((const float*)base)[src]) : ((const short*)base)[src];
    ((short*)Wf)[idx] = v;
}

// ================= sort by dst (counting sort) =================
__global__ void k_hist(const void* __restrict__ ei, int* __restrict__ deg,
                       const int* __restrict__ flags) {
    bool i64 = (flags[1] == 1);
    for (int e = blockIdx.x * 256 + threadIdx.x; e < NEDGES; e += gridDim.x * 256) {
        int d = i64 ? (int)((const long long*)ei)[NEDGES + e] : ((const int*)ei)[NEDGES + e];
        if ((unsigned)d < NNODES) atomicAdd(&deg[d], 1);
    }
}

__global__ __launch_bounds__(1024) void k_scan(const int* __restrict__ deg,
                                               int* __restrict__ rowptr) {
    __shared__ int part[1024];
    const int CH = 49;
    int t = threadIdx.x;
    int lo = t * CH, hi = lo + CH; if (hi > NNODES) hi = NNODES; if (lo > NNODES) lo = NNODES;
    int s = 0;
    for (int i = lo; i < hi; ++i) s += deg[i];
    part[t] = s;
    __syncthreads();
    for (int off = 1; off < 1024; off <<= 1) {
        int v = (t >= off) ? part[t - off] : 0;
        __syncthreads();
        part[t] += v;
        __syncthreads();
    }
    int run = (t == 0) ? 0 : part[t - 1];
    for (int i = lo; i < hi; ++i) { rowptr[i] = run; run += deg[i]; }
    if (t == 1023) rowptr[NNODES] = run;
}

__global__ void k_scatter(const void* __restrict__ ei, const int* __restrict__ rowptr,
                          int* __restrict__ cursor, int* __restrict__ srcs,
                          int* __restrict__ dsts, int* __restrict__ eids,
                          int* __restrict__ pos_of,
                          const int* __restrict__ flags) {
    bool i64 = (flags[1] == 1);
    for (int e = blockIdx.x * 256 + threadIdx.x; e < NEDGES; e += gridDim.x * 256) {
        int s, d;
        if (i64) {
            s = (int)((const long long*)ei)[e];
            d = (int)((const long long*)ei)[NEDGES + e];
        } else {
            s = ((const int*)ei)[e];
            d = ((const int*)ei)[NEDGES + e];
        }
        if ((unsigned)s >= NNODES || (unsigned)d >= NNODES) { pos_of[e] = -1; continue; }
        int pos = rowptr[d] + atomicAdd(&cursor[d], 1);
        srcs[pos] = s; dsts[pos] = d; eids[pos] = e; pos_of[e] = pos;
    }
}

// ---------- permute-gather of edge_attr, LINEAR coalesced read / random row write
__global__ void k_permEA3(const void* __restrict__ EA, const int* __restrict__ pos_of,
                          bf16* __restrict__ eaP, const int* __restrict__ flags) {
    bool f32 = (flags[0] == 0);
    int tid = blockIdx.x * 256 + threadIdx.x;
    int t = tid & 7;
    int r0 = (tid >> 3) * 4;
    if (r0 >= NEDGES) return;
    int p[4];
#pragma unroll
    for (int j = 0; j < 4; ++j) p[j] = pos_of[r0 + j];
    if (f32) {
        float4 a[4], b[4];
#pragma unroll
        for (int j = 0; j < 4; ++j) {
            const float4* q = reinterpret_cast<const float4*>(
                (const float*)EA + (size_t)(r0 + j) * 64 + t * 8);
            a[j] = q[0]; b[j] = q[1];
        }
#pragma unroll
        for (int j = 0; j < 4; ++j) {
            if (p[j] < 0) continue;
            bf16x8 r;
            r[0]=f2bs(a[j].x); r[1]=f2bs(a[j].y); r[2]=f2bs(a[j].z); r[3]=f2bs(a[j].w);
            r[4]=f2bs(b[j].x); r[5]=f2bs(b[j].y); r[6]=f2bs(b[j].z); r[7]=f2bs(b[j].w);
            *reinterpret_cast<bf16x8*>(eaP + (size_t)p[j] * 64 + t * 8) = r;
        }
    } else {
        bf16x8 a[4];
#pragma unroll
        for (int j = 0; j < 4; ++j)
            a[j] = *reinterpret_cast<const bf16x8*>(
                (const bf16*)EA + (size_t)(r0 + j) * 64 + t * 8);
#pragma unroll
        for (int j = 0; j < 4; ++j) {
            if (p[j] < 0) continue;
            *reinterpret_cast<bf16x8*>(eaP + (size_t)p[j] * 64 + t * 8) = a[j];
        }
    }
}

// ================= GEMM with fused bias + BN column stats =================
template<int K, int NF>
__global__ __launch_bounds__(256) void k_gemm(const void* __restrict__ A,
                                              const bf16* __restrict__ Wf,
                                              const bf16* __restrict__ bias,
                                              bf16* __restrict__ Y, int M,
                                              float* __restrict__ ssum,
                                              float* __restrict__ ssq,
                                              const int* __restrict__ flags, int flexA) {
    const int N = NF * 16;
    __shared__ float sred[2][4][N];
    bool f32 = flexA && (flags[0] == 0);
    int lane = threadIdx.x & 63, wave = threadIdx.x >> 6;
    int rowbase = blockIdx.x * 64 + wave * 16;
    int arow = rowbase + (lane & 15);
    bool aval = (arow < M);
    size_t abase = (size_t)arow * K + ((lane >> 4) << 3);
    f32x4 acc[NF] = {};
#pragma unroll
    for (int ks = 0; ks < K / 32; ++ks) {
        bf16x8 a = aval ? ld_a8(A, abase + ks * 32, f32) : zero8();
#pragma unroll
        for (int f = 0; f < NF; ++f) {
            bf16x8 b = ld_frag(Wf + (((ks * NF + f) * 64 + lane) << 3));
            acc[f] = __builtin_amdgcn_mfma_f32_16x16x32_bf16(a, b, acc[f], 0, 0, 0);
        }
    }
    int hi = lane >> 4, coll = lane & 15;
    int crow = rowbase + hi * 4;
#pragma unroll
    for (int f = 0; f < NF; ++f) {
        int col = f * 16 + coll;
        float bv = b2f(bias[col]);
        float s = 0.f, q = 0.f;
#pragma unroll
        for (int r = 0; r < 4; ++r) {
            int row = crow + r;
            if (row < M) {
                float v = acc[f][r] + bv;
                Y[(size_t)row * N + col] = __float2bfloat16(v);
                s += v; q += v * v;
            }
        }
        s += __shfl_xor(s, 16); s += __shfl_xor(s, 32);
        q += __shfl_xor(q, 16); q += __shfl_xor(q, 32);
        if (hi == 0) { sred[0][wave][col] = s; sred[1][wave][col] = q; }
    }
    __syncthreads();
    for (int t = threadIdx.x; t < N; t += 256) {
        float s = sred[0][0][t] + sred[0][1][t] + sred[0][2][t] + sred[0][3][t];
        float q = sred[1][0][t] + sred[1][1][t] + sred[1][2][t] + sred[1][3][t];
        atomicAdd(&ssum[t], s); atomicAdd(&ssq[t], q);
    }
}

// ======= GEMM with fused zin input (A = bf16((1+eps)h + agg)), K=128 =======
// Y aliases agg; each block reads exactly the rows it writes; invalid rows -> zero frags.
template<int NF>
__global__ __launch_bounds__(256) void k_gemm_zin(const bf16* __restrict__ h,
                                                  const float* __restrict__ agg,
                                                  const bf16* __restrict__ epsc, int layer,
                                                  const bf16* __restrict__ Wf,
                                                  const bf16* __restrict__ bias,
                                                  bf16* __restrict__ Y, int M,
                                                  float* __restrict__ ssum,
                                                  float* __restrict__ ssq) {
    const int K = 128, N = NF * 16;
    __shared__ float sred[2][4][N];
    float e1 = 1.f + b2f(epsc[layer]);
    int lane = threadIdx.x & 63, wave = threadIdx.x >> 6;
    int rowbase = blockIdx.x * 64 + wave * 16;
    int arow = rowbase + (lane & 15);
    bool aval = (arow < M);
    size_t abase = (size_t)arow * K + ((lane >> 4) << 3);
    f32x4 acc[NF] = {};
#pragma unroll
    for (int ks = 0; ks < 4; ++ks) {
        bf16x8 a;
        if (aval) {
            size_t off = abase + ks * 32;
            bf16x8 hv = ld_frag(h + off);
            float4 a0 = *reinterpret_cast<const float4*>(agg + off);
            float4 a1 = *reinterpret_cast<const float4*>(agg + off + 4);
            a[0] = f2bs(e1 * bs2f(hv[0]) + a0.x);
            a[1] = f2bs(e1 * bs2f(hv[1]) + a0.y);
            a[2] = f2bs(e1 * bs2f(hv[2]) + a0.z);
            a[3] = f2bs(e1 * bs2f(hv[3]) + a0.w);
            a[4] = f2bs(e1 * bs2f(hv[4]) + a1.x);
            a[5] = f2bs(e1 * bs2f(hv[5]) + a1.y);
            a[6] = f2bs(e1 * bs2f(hv[6]) + a1.z);
            a[7] = f2bs(e1 * bs2f(hv[7]) + a1.w);
        } else {
            a = zero8();
        }
#pragma unroll
        for (int f = 0; f < NF; ++f) {
            bf16x8 b = ld_frag(Wf + (((ks * NF + f) * 64 + lane) << 3));
            acc[f] = __builtin_amdgcn_mfma_f32_16x16x32_bf16(a, b, acc[f], 0, 0, 0);
        }
    }
    int hi = lane >> 4, coll = lane & 15;
    int crow = rowbase + hi * 4;
#pragma unroll
    for (int f = 0; f < NF; ++f) {
        int col = f * 16 + coll;
        float bv = b2f(bias[col]);
        float s = 0.f, q = 0.f;
#pragma unroll
        for (int r = 0; r < 4; ++r) {
            int row = crow + r;
            if (row < M) {
                float v = acc[f][r] + bv;
                Y[(size_t)row * N + col] = __float2bfloat16(v);
                s += v; q += v * v;
            }
        }
        s += __shfl_xor(s, 16); s += __shfl_xor(s, 32);
        q += __shfl_xor(q, 16); q += __shfl_xor(q, 32);
        if (hi == 0) { sred[0][wave][col] = s; sred[1][wave][col] = q; }
    }
    __syncthreads();
    for (int t = threadIdx.x; t < N; t += 256) {
        float s = sred[0][0][t] + sred[0][1][t] + sred[0][2][t] + sred[0][3][t];
        float q = sred[1][0][t] + sred[1][1][t] + sred[1][2][t] + sred[1][3][t];
        atomicAdd(&ssum[t], s); atomicAdd(&ssq[t], q);
    }
}

// ======= GEMM with fused BN+GELU on A (A = gelu(bn(y1raw))), K=256 =======
template<int NF>
__global__ __launch_bounds__(256) void k_gemm_bn(const bf16* __restrict__ A,
                                                 const float* __restrict__ ssumIn,
                                                 const float* __restrict__ ssqIn,
                                                 const bf16* __restrict__ gIn,
                                                 const bf16* __restrict__ btIn,
                                                 const bf16* __restrict__ Wf,
                                                 const bf16* __restrict__ bias,
                                                 bf16* __restrict__ Y, int M,
                                                 float* __restrict__ ssum,
                                                 float* __restrict__ ssq) {
    const int K = 256, N = NF * 16;
    __shared__ float sscale[K], sshift[K];
    __shared__ float sred[2][4][N];
    for (int c = threadIdx.x; c < K; c += 256) {
        const float invM = 1.f / (float)NNODES;
        float mean = ssumIn[c] * invM;
        float var  = ssqIn[c] * invM - mean * mean;
        float a = b2f(gIn[c]) * rsqrtf(fmaxf(var, 0.f) + 1e-5f);
        sscale[c] = a;
        sshift[c] = b2f(btIn[c]) - mean * a;
    }
    __syncthreads();
    int lane = threadIdx.x & 63, wave = threadIdx.x >> 6;
    int rowbase = blockIdx.x * 64 + wave * 16;
    int arow = rowbase + (lane & 15);
    bool aval = (arow < M);
    int koff = (lane >> 4) << 3;
    size_t abase = (size_t)arow * K + koff;
    f32x4 acc[NF] = {};
#pragma unroll
    for (int ks = 0; ks < 8; ++ks) {
        bf16x8 a;
        if (aval) {
            bf16x8 raw = ld_frag(A + abase + ks * 32);
            int c0 = ks * 32 + koff;
#pragma unroll
            for (int j = 0; j < 8; ++j) {
                float v = bs2f(raw[j]) * sscale[c0 + j] + sshift[c0 + j];
                a[j] = f2bs(gelu_ex(v));
            }
        } else {
            a = zero8();
        }
#pragma unroll
        for (int f = 0; f < NF; ++f) {
            bf16x8 b = ld_frag(Wf + (((ks * NF + f) * 64 + lane) << 3));
            acc[f] = __builtin_amdgcn_mfma_f32_16x16x32_bf16(a, b, acc[f], 0, 0, 0);
        }
    }
    int hi = lane >> 4, coll = lane & 15;
    int crow = rowbase + hi * 4;
#pragma unroll
    for (int f = 0; f < NF; ++f) {
        int col = f * 16 + coll;
        float bv = b2f(bias[col]);
        float s = 0.f, q = 0.f;
#pragma unroll
        for (int r = 0; r < 4; ++r) {
            int row = crow + r;
            if (row < M) {
                float v = acc[f][r] + bv;
                Y[(size_t)row * N + col] = __float2bfloat16(v);
                s += v; q += v * v;
            }
        }
        s += __shfl_xor(s, 16); s += __shfl_xor(s, 32);
        q += __shfl_xor(q, 16); q += __shfl_xor(q, 32);
        if (hi == 0) { sred[0][wave][col] = s; sred[1][wave][col] = q; }
    }
    __syncthreads();
    for (int t = threadIdx.x; t < N; t += 256) {
        float s = sred[0][0][t] + sred[0][1][t] + sred[0][2][t] + sred[0][3][t];
        float q = sred[1][0][t] + sred[1][1][t] + sred[1][2][t] + sred[1][3][t];
        atomicAdd(&ssum[t], s); atomicAdd(&ssq[t], q);
    }
}

// ===== CSR node-parallel edge kernel, 2 waves/block (one node each), NO ATOMICS =====
// Per-wave body is byte-structured like the proven k_edge6; both waves loop to the
// PAIR MAX chunk count so every __syncthreads() is executed uniformly by both waves.
__global__ __launch_bounds__(128) void k_edge7(const bf16* __restrict__ eaP,
                                               const void* __restrict__ EA,
                                               const int* __restrict__ eids,
                                               const bf16* __restrict__ Wf,
                                               const bf16* __restrict__ bias,
                                               const int* __restrict__ srcs,
                                               const int* __restrict__ rowptr,
                                               const bf16* __restrict__ h,
                                               float* __restrict__ agg,
                                               const int* __restrict__ flags) {
    __shared__ short sm[2][16 * 132];
    __shared__ int nck[2];
    bool f32 = (flags[0] == 0);
    int lane = threadIdx.x & 63, wave = threadIdx.x >> 6;
    int d = blockIdx.x * 2 + wave;               // grid = NNODES/2, d < NNODES always
    int start = rowptr[d], end = rowptr[d + 1];
    int mychunks = (end - start + 15) >> 4;
    if (lane == 0) nck[wave] = mychunks;
    __syncthreads();
    int maxc = nck[0] > nck[1] ? nck[0] : nck[1];
    int koff = (lane >> 4) << 3;
    int l2 = lane * 2;
    int hi = lane >> 4, coll = lane & 15;
    int rbase = hi * 4;
    float bx = b2f(bias[l2]), by = b2f(bias[l2 + 1]);
    float rx = 0.f, ry = 0.f;
    for (int ci = 0; ci < maxc; ++ci) {
        bool active = (ci < mychunks);
        int c = start + ci * 16;
        int eidx = c + (lane & 15);
        int ok_l = (active && eidx < end) ? 1 : 0;
        int sc_l = ok_l ? srcs[eidx] : 0;
        f32x4 acc[8] = {};
        if (active) {
            if (eaP) {
                const bf16* ap = eaP + (size_t)eidx * 64 + koff;
#pragma unroll
                for (int ks = 0; ks < 2; ++ks) {
                    bf16x8 a = ok_l ? ld_frag(ap + ks * 32) : zero8();
#pragma unroll
                    for (int f = 0; f < 8; ++f) {
                        bf16x8 b = ld_frag(Wf + (((ks * 8 + f) * 64 + lane) << 3));
                        acc[f] = __builtin_amdgcn_mfma_f32_16x16x32_bf16(a, b, acc[f], 0, 0, 0);
                    }
                }
            } else {
                size_t abase = ok_l ? ((size_t)eids[eidx] * 64 + koff) : 0;
#pragma unroll
                for (int ks = 0; ks < 2; ++ks) {
                    bf16x8 a = ok_l ? ld_a8(EA, abase + ks * 32, f32) : zero8();
#pragma unroll
                    for (int f = 0; f < 8; ++f) {
                        bf16x8 b = ld_frag(Wf + (((ks * 8 + f) * 64 + lane) << 3));
                        acc[f] = __builtin_amdgcn_mfma_f32_16x16x32_bf16(a, b, acc[f], 0, 0, 0);
                    }
                }
            }
        }
        // prefetch h rows for this chunk (independent coalesced loads)
        unsigned hv[16];
#pragma unroll
        for (int e = 0; e < 16; ++e) {
            int s = __shfl(sc_l, e);
            hv[e] = active ? *reinterpret_cast<const unsigned*>(
                reinterpret_cast<const unsigned short*>(h) + (size_t)s * 128 + l2) : 0u;
        }
        if (ci > 0) __syncthreads();   // uniform: ci identical across waves
        if (active) {
#pragma unroll
            for (int f = 0; f < 8; ++f)
#pragma unroll
                for (int r = 0; r < 4; ++r)
                    sm[wave][(rbase + r) * 132 + f * 16 + coll] = f2bs(acc[f][r]);
        }
        __syncthreads();               // uniform: executed by both waves every ci
        if (active) {
            int lim = end - c; if (lim > 16) lim = 16;
            for (int e = 0; e < lim; ++e) {
                unsigned mu = *reinterpret_cast<const unsigned*>(&sm[wave][e * 132 + l2]);
                float vx = u2f_lo(mu) + u2f_lo(hv[e]) + bx;
                float vy = u2f_hi(mu) + u2f_hi(hv[e]) + by;
                rx += fmaxf(vx, 0.f); ry += fmaxf(vy, 0.f);
            }
        }
    }
    // exclusive ownership of row d: plain store (zero-degree nodes store 0)
    agg[(size_t)d * 128 + l2]     = rx;
    agg[(size_t)d * 128 + l2 + 1] = ry;
}

// ---------- legacy unsorted edge kernel (tier C fallback)
__global__ __launch_bounds__(256) void k_edge(const void* __restrict__ EA,
                                              const bf16* __restrict__ Wf,
                                              const bf16* __restrict__ bias,
                                              const void* __restrict__ ei,
                                              const bf16* __restrict__ h,
                                              float* __restrict__ agg,
                                              const int* __restrict__ flags) {
    bool f32 = (flags[0] == 0);
    bool i64 = (flags[1] == 1);
    const int K = 64, NF = 8;
    int lane = threadIdx.x & 63, wave = threadIdx.x >> 6;
    int rowbase = blockIdx.x * 64 + wave * 16;
    int colbase = blockIdx.y * 64;
    int arow = rowbase + (lane & 15);
    size_t abase = (size_t)arow * K + ((lane >> 4) << 3);
    f32x4 acc[4] = {};
#pragma unroll
    for (int ks = 0; ks < 2; ++ks) {
        bf16x8 a = ld_a8(EA, abase + ks * 32, f32);
#pragma unroll
        for (int f = 0; f < 4; ++f) {
            bf16x8 b = ld_frag(Wf + (((ks * NF + colbase / 16 + f) * 64 + lane) << 3));
            acc[f] = __builtin_amdgcn_mfma_f32_16x16x32_bf16(a, b, acc[f], 0, 0, 0);
        }
    }
    int erow = rowbase + ((lane >> 4) << 2);
    int coll = lane & 15;
    float bv[4];
#pragma unroll
    for (int f = 0; f < 4; ++f) bv[f] = b2f(bias[colbase + f * 16 + coll]);
#pragma unroll
    for (int r = 0; r < 4; ++r) {
        int e = erow + r;
        int s, d;
        if (i64) {
            s = (int)((const long long*)ei)[e];
            d = (int)((const long long*)ei)[NEDGES + e];
        } else {
            s = ((const int*)ei)[e];
            d = ((const int*)ei)[NEDGES + e];
        }
        if ((unsigned)s >= NNODES || (unsigned)d >= NNODES) continue;
        const bf16* hp = h + (size_t)s * HIDDEN;
        float* gp = agg + (size_t)d * HIDDEN;
#pragma unroll
        for (int f = 0; f < 4; ++f) {
            int col = colbase + f * 16 + coll;
            float v = acc[f][r] + bv[f] + b2f(hp[col]);
            if (v > 0.f) atomicAdd(gp + col, v);
        }
    }
}

// ---------- fused BN-finalize + normalize + exact GELU (x4) + optional agg-zero tail
template<int N>
__global__ void k_bngelu4(const bf16* __restrict__ y, const float* __restrict__ ssum,
                          const float* __restrict__ ssq, const bf16* __restrict__ g,
                          const bf16* __restrict__ beta, bf16* __restrict__ z,
                          void* __restrict__ out_base, int slice,
                          const int* __restrict__ flags,
                          float* __restrict__ aggz, int aggn4) {
    __shared__ float sscale[N], sshift[N];
    for (int c = threadIdx.x; c < N; c += 256) {
        const float invM = 1.f / (float)NNODES;
        float mean = ssum[c] * invM;
        float var  = ssq[c] * invM - mean * mean;
        float a = b2f(g[c]) * rsqrtf(fmaxf(var, 0.f) + 1e-5f);
        sscale[c] = a;
        sshift[c] = b2f(beta[c]) - mean * a;
    }
    __syncthreads();
    bool outb = (flags[0] == 1);
    const int total4 = NNODES * N / 4;
    for (int i4 = blockIdx.x * 256 + threadIdx.x; i4 < total4; i4 += gridDim.x * 256) {
        int i = i4 * 4;
        int col = i & (N - 1);
        ushort4 yv = ((const ushort4*)y)[i4];
        float g0 = gelu_ex(u2f_lo(yv.x) * sscale[col]     + sshift[col]);
        float g1 = gelu_ex(u2f_lo(yv.y) * sscale[col + 1] + sshift[col + 1]);
        float g2 = gelu_ex(u2f_lo(yv.z) * sscale[col + 2] + sshift[col + 2]);
        float g3 = gelu_ex(u2f_lo(yv.w) * sscale[col + 3] + sshift[col + 3]);
        ushort4 zv;
        zv.x = (unsigned short)f2bs(g0); zv.y = (unsigned short)f2bs(g1);
        zv.z = (unsigned short)f2bs(g2); zv.w = (unsigned short)f2bs(g3);
        ((ushort4*)z)[i4] = zv;
        if (slice >= 0) {
            int row = i / N;
            size_t ob = (size_t)row * 512 + (size_t)slice * 128 + col;
            if (outb) {
                *reinterpret_cast<ushort4*>((unsigned short*)out_base + ob) = zv;
            } else {
                float4 gv = {g0, g1, g2, g3};
                *reinterpret_cast<float4*>((float*)out_base + ob) = gv;
            }
        }
    }
    if (aggz) {
        float4 zzz = {0.f, 0.f, 0.f, 0.f};
        for (int i4 = blockIdx.x * 256 + threadIdx.x; i4 < aggn4; i4 += gridDim.x * 256)
            ((float4*)aggz)[i4] = zzz;
    }
}

extern "C" void kernel_launch(void* const* d_in, const int* in_sizes, int n_in,
                              void* d_out, int out_size, void* d_ws, size_t ws_size,
                              hipStream_t stream) {
    const void* x      = d_in[0];
    const void* ei     = d_in[1];
    const void* ea     = d_in[2];
    const void* emb_w  = d_in[3];
    const void* emb_b  = d_in[4];
    const void* emb_g  = d_in[5];
    const void* emb_bt = d_in[6];
    const void* eps    = d_in[7];
    const void* lin_w  = d_in[8];
    const void* lin_b  = d_in[9];
    const void* w1     = d_in[10];
    const void* b1     = d_in[11];
    const void* g1     = d_in[12];
    const void* bt1    = d_in[13];
    const void* w2     = d_in[14];
    const void* b2     = d_in[15];
    const void* g2     = d_in[16];
    const void* bt2    = d_in[17];

    char* ws = (char*)d_ws;
    int*   flags  = (int*)ws;
    float* stats  = (float*)(ws + 1024);
    bf16*  canon  = (bf16*)(ws + 16384);
    bf16*  wf0    = (bf16*)(ws + 32768);
    bf16*  lin_wf = wf0 + 16384;
    bf16*  w1f    = wf0 + 40960;
    bf16*  w2f    = wf0 + 139264;
    bf16*  bufH   = (bf16*)(ws + 524288);       // [50000,128] bf16 (y0 / h)
    bf16*  bufA   = (bf16*)(ws + 13324288);     // [50000,128] bf16 (y2)
    char*  bufC   = (ws + 26124288);            // 25.6 MB (agg fp32 | y1 bf16)
    float* aggf   = (float*)bufC;
    bf16*  y1     = (bf16*)bufC;
    const size_t SB = 51724288;
    int*  rowptr  = (int*)(ws + SB);
    int*  cursorA = (int*)(ws + SB + 200704);
    int*  srcs    = (int*)(ws + SB + 401408);
    int*  dsts    = (int*)(ws + SB + 3601408);
    int*  eids    = (int*)(ws + SB + 6801408);
    bf16* eaP     = (bf16*)(ws + SB + 10001408);
    int*  cursorB = (int*)bufA;                       // dead region during sort phase
    int*  pos_of  = (int*)(ws + 13324288 + 1048576);  // bufA+1MB, dead during sort phase
    const unsigned long long TIERA_NEED = SB + 10001408ull + 102400000ull;
    const unsigned long long TIERB_NEED = SB + 10001408ull;
    bool tierA = ws_size >= TIERA_NEED;
    bool tierB = !tierA && ws_size >= TIERB_NEED;
    bool sorted = tierA || tierB;
    const int AGGN4 = NNODES * HIDDEN / 4;

    k_init<<<256, 256, 0, stream>>>(stats, cursorA, cursorB, sorted ? 1 : 0);
    k_detect_cvt<<<1, 256, 0, stream>>>((const unsigned*)emb_g, (const unsigned*)ei, flags,
                                        emb_b, emb_g, emb_bt, eps, lin_b, b1, g1, bt1,
                                        b2, g2, bt2, canon);
    k_repack_all<<<928, 256, 0, stream>>>(emb_w, lin_w, w1, w2, wf0, flags);

    if (sorted) {
        k_hist<<<1024, 256, 0, stream>>>(ei, cursorA, flags);
        k_scan<<<1, 1024, 0, stream>>>(cursorA, rowptr);
        k_scatter<<<1024, 256, 0, stream>>>(ei, rowptr, cursorB, srcs, dsts, eids,
                                            pos_of, flags);
        if (tierA) k_permEA3<<<6250, 256, 0, stream>>>(ea, pos_of, eaP, flags);
    }

    // ---- node embed (stats slot 0); tier-C needs agg pre-zeroed via bngelu tail
    float* aggz0 = sorted ? (float*)nullptr : aggf;
    k_gemm<128, 8><<<782, 256, 0, stream>>>(x, wf0, canon + C_EMB_B, bufH, NNODES,
                                            stats, stats + 256, flags, 1);
    k_bngelu4<128><<<2048, 256, 0, stream>>>(bufH, stats, stats + 256,
                                             canon + C_EMB_G, canon + C_EMB_BT,
                                             bufH, d_out, 0, flags, aggz0, AGGN4);

    for (int i = 0; i < 3; ++i) {
        float* s1 = stats + (size_t)(1 + 2 * i) * 512;
        float* s2 = stats + (size_t)(2 + 2 * i) * 512;
        if (tierA)
            k_edge7<<<NNODES / 2, 128, 0, stream>>>(eaP, (const void*)nullptr,
                                                    (const int*)nullptr,
                                                    lin_wf + i * 8192, canon + C_LIN_B + i * 128,
                                                    srcs, rowptr, bufH, aggf, flags);
        else if (tierB)
            k_edge7<<<NNODES / 2, 128, 0, stream>>>((const bf16*)nullptr, ea, eids,
                                                    lin_wf + i * 8192, canon + C_LIN_B + i * 128,
                                                    srcs, rowptr, bufH, aggf, flags);
        else
            k_edge<<<dim3(12500, 2), 256, 0, stream>>>(ea, lin_wf + i * 8192,
                                                       canon + C_LIN_B + i * 128, ei,
                                                       bufH, aggf, flags);
        // MLP layer 1 with fused zin (stats slot 1+2i); y1 = raw pre-BN output
        k_gemm_zin<16><<<782, 256, 0, stream>>>(bufH, aggf, canon + C_EPS, i,
                                                w1f + i * 32768, canon + C_B1 + i * 256,
                                                y1, NNODES, s1, s1 + 256);
        // MLP layer 2 with consumer-fused BN+GELU on y1 (stats slot 2+2i)
        k_gemm_bn<8><<<782, 256, 0, stream>>>(y1, s1, s1 + 256, canon + C_G1 + i * 256,
                                              canon + C_BT1 + i * 256,
                                              w2f + i * 32768, canon + C_B2 + i * 128,
                                              bufA, NNODES, s2, s2 + 256);
        // slice bngelu; tier-C zero-tail for next layer's atomics (sorted path: none)
        float* aggz = (!sorted && i < 2) ? aggf : (float*)nullptr;
        k_bngelu4<128><<<2048, 256, 0, stream>>>(bufA, s2, s2 + 256, canon + C_G2 + i * 128,
                                                 canon + C_BT2 + i * 128, bufH, d_out,
                                                 i + 1, flags, aggz, AGGN4);
    }
}

// Round 15
// 894.775 us; speedup vs baseline: 1.1262x; 1.1262x over previous
//
#include <hip/hip_runtime.h>
#include <hip/hip_bf16.h>

typedef __hip_bfloat16 bf16;
typedef __attribute__((ext_vector_type(8))) short bf16x8;
typedef __attribute__((ext_vector_type(4))) float f32x4;

#define HIDDEN 128
#define NNODES 50000
#define NEDGES 800000

static __device__ __forceinline__ float b2f(bf16 v) { return __bfloat162float(v); }
static __device__ __forceinline__ short f2bs(float f) {
    bf16 b = __float2bfloat16(f);
    return *reinterpret_cast<const short*>(&b);
}
static __device__ __forceinline__ float bs2f(short s) {
    unsigned x = ((unsigned)(unsigned short)s) << 16;
    return *reinterpret_cast<const float*>(&x);
}
static __device__ __forceinline__ bf16x8 ld_frag(const bf16* p) {
    return *reinterpret_cast<const bf16x8*>(p);
}
static __device__ __forceinline__ bf16x8 zero8() {
    bf16x8 z = {0, 0, 0, 0, 0, 0, 0, 0};
    return z;
}
static __device__ __forceinline__ float u2f_lo(unsigned u) {
    unsigned x = u << 16; return *reinterpret_cast<const float*>(&x);
}
static __device__ __forceinline__ float u2f_hi(unsigned u) {
    unsigned x = u & 0xffff0000u; return *reinterpret_cast<const float*>(&x);
}
static __device__ __forceinline__ bf16x8 ld_a8(const void* base, size_t off, bool f32) {
    if (!f32) return *reinterpret_cast<const bf16x8*>((const bf16*)base + off);
    const float4* p = reinterpret_cast<const float4*>((const float*)base + off);
    float4 u = p[0], w = p[1];
    bf16x8 r;
    r[0]=f2bs(u.x); r[1]=f2bs(u.y); r[2]=f2bs(u.z); r[3]=f2bs(u.w);
    r[4]=f2bs(w.x); r[5]=f2bs(w.y); r[6]=f2bs(w.z); r[7]=f2bs(w.w);
    return r;
}
static __device__ __forceinline__ float gelu_ex(float v) {
    return 0.5f * v * (1.f + erff(v * 0.70710678118654752f));
}

#define C_EMB_B   0
#define C_EMB_G   128
#define C_EMB_BT  256
#define C_EPS     384
#define C_LIN_B   400
#define C_B1      800
#define C_G1      1568
#define C_BT1     2336
#define C_B2      3104
#define C_G2      3488
#define C_BT2     3872

__global__ void k_init(float* __restrict__ stats, int* __restrict__ cursorA,
                       int* __restrict__ cursorB, int doSort) {
    int tid = blockIdx.x * 256 + threadIdx.x;
    int stride = gridDim.x * 256;
    for (int i = tid; i < 3584; i += stride) stats[i] = 0.f;
    if (doSort) for (int i = tid; i < NNODES; i += stride) cursorA[i] = 0;
    for (int i = tid; i < NNODES; i += stride) cursorB[i] = 0;
}

__global__ void k_detect_cvt(const unsigned* __restrict__ gones,
                             const unsigned* __restrict__ eiw, int* __restrict__ flags,
                             const void* emb_b, const void* emb_g, const void* emb_bt,
                             const void* eps, const void* lin_b, const void* b1,
                             const void* g1, const void* bt1, const void* b2,
                             const void* g2, const void* bt2, bf16* __restrict__ canon) {
    __shared__ int sf;
    if (threadIdx.x == 0) {
        int f0 = (gones[0] == 0x3F803F80u) ? 1 : 0;
        unsigned s = 0;
        for (int i = 1; i < 64; i += 2) s |= eiw[i];
        flags[0] = f0; flags[1] = (s == 0u) ? 1 : 0;
        sf = f0;
    }
    __syncthreads();
    bool f32 = (sf == 0);
    const void* ps[11] = {emb_b, emb_g, emb_bt, eps, lin_b, b1, g1, bt1, b2, g2, bt2};
    const int   ns[11] = {128, 128, 128, 3, 384, 768, 768, 768, 384, 384, 384};
    const int   os[11] = {C_EMB_B, C_EMB_G, C_EMB_BT, C_EPS, C_LIN_B, C_B1,
                          C_G1, C_BT1, C_B2, C_G2, C_BT2};
    for (int seg = 0; seg < 11; ++seg)
        for (int i = threadIdx.x; i < ns[seg]; i += 256) {
            short v = f32 ? f2bs(((const float*)ps[seg])[i]) : ((const short*)ps[seg])[i];
            ((short*)canon)[os[seg] + i] = v;
        }
}

__global__ void k_repack_all(const void* __restrict__ emb_w, const void* __restrict__ lin_w,
                             const void* __restrict__ w1, const void* __restrict__ w2,
                             bf16* __restrict__ Wf, const int* __restrict__ flags) {
    const int starts[11] = {0, 16384, 24576, 32768, 40960, 73728, 106496,
                            139264, 172032, 204800, 237568};
    int idx = blockIdx.x * 256 + threadIdx.x;
    if (idx >= 237568) return;
    bool f32 = (flags[0] == 0);
    int seg = 0;
    while (idx >= starts[seg + 1]) ++seg;
    int local = idx - starts[seg];
    const void* base; long long eoff; int K, N;
    if (seg == 0)      { base = emb_w; eoff = 0;                          K = 128; N = 128; }
    else if (seg <= 3) { base = lin_w; eoff = (long long)(seg - 1) * 8192;  K = 64;  N = 128; }
    else if (seg <= 6) { base = w1;    eoff = (long long)(seg - 4) * 32768; K = 128; N = 256; }
    else               { base = w2;    eoff = (long long)(seg - 7) * 32768; K = 256; N = 128; }
    int j    = local & 7;
    int lane = (local >> 3) & 63;
    int rest = local >> 9;
    int NF   = N >> 4;
    int ks   = rest / NF;
    int nf   = rest - ks * NF;
    int k = ks * 32 + ((lane >> 4) << 3) + j;
    int n = (nf << 4) + (lane & 15);
    long long src = eoff + (long long)k * N + n;
    short v = f32 ? f2bs(((const float*)base)[src]) : ((const short*)base)[src];
    ((short*)Wf)[idx] = v;
}

// ================= sort by dst (counting sort) =================
__global__ void k_hist(const void* __restrict__ ei, int* __restrict__ deg,
                       const int* __restrict__ flags) {
    bool i64 = (flags[1] == 1);
    for (int e = blockIdx.x * 256 + threadIdx.x; e < NEDGES; e += gridDim.x * 256) {
        int d = i64 ? (int)((const long long*)ei)[NEDGES + e] : ((const int*)ei)[NEDGES + e];
        if ((unsigned)d < NNODES) atomicAdd(&deg[d], 1);
    }
}

__global__ __launch_bounds__(1024) void k_scan(const int* __restrict__ deg,
                                               int* __restrict__ rowptr) {
    __shared__ int part[1024];
    const int CH = 49;
    int t = threadIdx.x;
    int lo = t * CH, hi = lo + CH; if (hi > NNODES) hi = NNODES; if (lo > NNODES) lo = NNODES;
    int s = 0;
    for (int i = lo; i < hi; ++i) s += deg[i];
    part[t] = s;
    __syncthreads();
    for (int off = 1; off < 1024; off <<= 1) {
        int v = (t >= off) ? part[t - off] : 0;
        __syncthreads();
        part[t] += v;
        __syncthreads();
    }
    int run = (t == 0) ? 0 : part[t - 1];
    for (int i = lo; i < hi; ++i) { rowptr[i] = run; run += deg[i]; }
    if (t == 1023) rowptr[NNODES] = run;
}

__global__ void k_scatter(const void* __restrict__ ei, const int* __restrict__ rowptr,
                          int* __restrict__ cursor, int* __restrict__ srcs,
                          int* __restrict__ dsts, int* __restrict__ eids,
                          int* __restrict__ pos_of,
                          const int* __restrict__ flags) {
    bool i64 = (flags[1] == 1);
    for (int e = blockIdx.x * 256 + threadIdx.x; e < NEDGES; e += gridDim.x * 256) {
        int s, d;
        if (i64) {
            s = (int)((const long long*)ei)[e];
            d = (int)((const long long*)ei)[NEDGES + e];
        } else {
            s = ((const int*)ei)[e];
            d = ((const int*)ei)[NEDGES + e];
        }
        if ((unsigned)s >= NNODES || (unsigned)d >= NNODES) { pos_of[e] = -1; continue; }
        int pos = rowptr[d] + atomicAdd(&cursor[d], 1);
        srcs[pos] = s; dsts[pos] = d; eids[pos] = e; pos_of[e] = pos;
    }
}

// ---------- permute-gather of edge_attr, LINEAR coalesced read / random row write
__global__ void k_permEA3(const void* __restrict__ EA, const int* __restrict__ pos_of,
                          bf16* __restrict__ eaP, const int* __restrict__ flags) {
    bool f32 = (flags[0] == 0);
    int tid = blockIdx.x * 256 + threadIdx.x;
    int t = tid & 7;
    int r0 = (tid >> 3) * 4;
    if (r0 >= NEDGES) return;
    int p[4];
#pragma unroll
    for (int j = 0; j < 4; ++j) p[j] = pos_of[r0 + j];
    if (f32) {
        float4 a[4], b[4];
#pragma unroll
        for (int j = 0; j < 4; ++j) {
            const float4* q = reinterpret_cast<const float4*>(
                (const float*)EA + (size_t)(r0 + j) * 64 + t * 8);
            a[j] = q[0]; b[j] = q[1];
        }
#pragma unroll
        for (int j = 0; j < 4; ++j) {
            if (p[j] < 0) continue;
            bf16x8 r;
            r[0]=f2bs(a[j].x); r[1]=f2bs(a[j].y); r[2]=f2bs(a[j].z); r[3]=f2bs(a[j].w);
            r[4]=f2bs(b[j].x); r[5]=f2bs(b[j].y); r[6]=f2bs(b[j].z); r[7]=f2bs(b[j].w);
            *reinterpret_cast<bf16x8*>(eaP + (size_t)p[j] * 64 + t * 8) = r;
        }
    } else {
        bf16x8 a[4];
#pragma unroll
        for (int j = 0; j < 4; ++j)
            a[j] = *reinterpret_cast<const bf16x8*>(
                (const bf16*)EA + (size_t)(r0 + j) * 64 + t * 8);
#pragma unroll
        for (int j = 0; j < 4; ++j) {
            if (p[j] < 0) continue;
            *reinterpret_cast<bf16x8*>(eaP + (size_t)p[j] * 64 + t * 8) = a[j];
        }
    }
}

// ================= GEMM with fused bias + BN column stats =================
template<int K, int NF>
__global__ __launch_bounds__(256) void k_gemm(const void* __restrict__ A,
                                              const bf16* __restrict__ Wf,
                                              const bf16* __restrict__ bias,
                                              bf16* __restrict__ Y, int M,
                                              float* __restrict__ ssum,
                                              float* __restrict__ ssq,
                                              const int* __restrict__ flags, int flexA) {
    const int N = NF * 16;
    __shared__ float sred[2][4][N];
    bool f32 = flexA && (flags[0] == 0);
    int lane = threadIdx.x & 63, wave = threadIdx.x >> 6;
    int rowbase = blockIdx.x * 64 + wave * 16;
    int arow = rowbase + (lane & 15);
    bool aval = (arow < M);
    size_t abase = (size_t)arow * K + ((lane >> 4) << 3);
    f32x4 acc[NF] = {};
#pragma unroll
    for (int ks = 0; ks < K / 32; ++ks) {
        bf16x8 a = aval ? ld_a8(A, abase + ks * 32, f32) : zero8();
#pragma unroll
        for (int f = 0; f < NF; ++f) {
            bf16x8 b = ld_frag(Wf + (((ks * NF + f) * 64 + lane) << 3));
            acc[f] = __builtin_amdgcn_mfma_f32_16x16x32_bf16(a, b, acc[f], 0, 0, 0);
        }
    }
    int hi = lane >> 4, coll = lane & 15;
    int crow = rowbase + hi * 4;
#pragma unroll
    for (int f = 0; f < NF; ++f) {
        int col = f * 16 + coll;
        float bv = b2f(bias[col]);
        float s = 0.f, q = 0.f;
#pragma unroll
        for (int r = 0; r < 4; ++r) {
            int row = crow + r;
            if (row < M) {
                float v = acc[f][r] + bv;
                Y[(size_t)row * N + col] = __float2bfloat16(v);
                s += v; q += v * v;
            }
        }
        s += __shfl_xor(s, 16); s += __shfl_xor(s, 32);
        q += __shfl_xor(q, 16); q += __shfl_xor(q, 32);
        if (hi == 0) { sred[0][wave][col] = s; sred[1][wave][col] = q; }
    }
    __syncthreads();
    for (int t = threadIdx.x; t < N; t += 256) {
        float s = sred[0][0][t] + sred[0][1][t] + sred[0][2][t] + sred[0][3][t];
        float q = sred[1][0][t] + sred[1][1][t] + sred[1][2][t] + sred[1][3][t];
        atomicAdd(&ssum[t], s); atomicAdd(&ssq[t], q);
    }
}

// ======= GEMM with fused zin input (A = bf16((1+eps)h + agg)), K=128 =======
template<int NF>
__global__ __launch_bounds__(256) void k_gemm_zin(const bf16* __restrict__ h,
                                                  const float* __restrict__ agg,
                                                  const bf16* __restrict__ epsc, int layer,
                                                  const bf16* __restrict__ Wf,
                                                  const bf16* __restrict__ bias,
                                                  bf16* __restrict__ Y, int M,
                                                  float* __restrict__ ssum,
                                                  float* __restrict__ ssq) {
    const int K = 128, N = NF * 16;
    __shared__ float sred[2][4][N];
    float e1 = 1.f + b2f(epsc[layer]);
    int lane = threadIdx.x & 63, wave = threadIdx.x >> 6;
    int rowbase = blockIdx.x * 64 + wave * 16;
    int arow = rowbase + (lane & 15);
    bool aval = (arow < M);
    size_t abase = (size_t)arow * K + ((lane >> 4) << 3);
    f32x4 acc[NF] = {};
#pragma unroll
    for (int ks = 0; ks < 4; ++ks) {
        bf16x8 a;
        if (aval) {
            size_t off = abase + ks * 32;
            bf16x8 hv = ld_frag(h + off);
            float4 a0 = *reinterpret_cast<const float4*>(agg + off);
            float4 a1 = *reinterpret_cast<const float4*>(agg + off + 4);
            a[0] = f2bs(e1 * bs2f(hv[0]) + a0.x);
            a[1] = f2bs(e1 * bs2f(hv[1]) + a0.y);
            a[2] = f2bs(e1 * bs2f(hv[2]) + a0.z);
            a[3] = f2bs(e1 * bs2f(hv[3]) + a0.w);
            a[4] = f2bs(e1 * bs2f(hv[4]) + a1.x);
            a[5] = f2bs(e1 * bs2f(hv[5]) + a1.y);
            a[6] = f2bs(e1 * bs2f(hv[6]) + a1.z);
            a[7] = f2bs(e1 * bs2f(hv[7]) + a1.w);
        } else {
            a = zero8();
        }
#pragma unroll
        for (int f = 0; f < NF; ++f) {
            bf16x8 b = ld_frag(Wf + (((ks * NF + f) * 64 + lane) << 3));
            acc[f] = __builtin_amdgcn_mfma_f32_16x16x32_bf16(a, b, acc[f], 0, 0, 0);
        }
    }
    int hi = lane >> 4, coll = lane & 15;
    int crow = rowbase + hi * 4;
#pragma unroll
    for (int f = 0; f < NF; ++f) {
        int col = f * 16 + coll;
        float bv = b2f(bias[col]);
        float s = 0.f, q = 0.f;
#pragma unroll
        for (int r = 0; r < 4; ++r) {
            int row = crow + r;
            if (row < M) {
                float v = acc[f][r] + bv;
                Y[(size_t)row * N + col] = __float2bfloat16(v);
                s += v; q += v * v;
            }
        }
        s += __shfl_xor(s, 16); s += __shfl_xor(s, 32);
        q += __shfl_xor(q, 16); q += __shfl_xor(q, 32);
        if (hi == 0) { sred[0][wave][col] = s; sred[1][wave][col] = q; }
    }
    __syncthreads();
    for (int t = threadIdx.x; t < N; t += 256) {
        float s = sred[0][0][t] + sred[0][1][t] + sred[0][2][t] + sred[0][3][t];
        float q = sred[1][0][t] + sred[1][1][t] + sred[1][2][t] + sred[1][3][t];
        atomicAdd(&ssum[t], s); atomicAdd(&ssq[t], q);
    }
}

// ======= GEMM with fused BN+GELU on A (A = gelu(bn(y1raw))), K=256 =======
template<int NF>
__global__ __launch_bounds__(256) void k_gemm_bn(const bf16* __restrict__ A,
                                                 const float* __restrict__ ssumIn,
                                                 const float* __restrict__ ssqIn,
                                                 const bf16* __restrict__ gIn,
                                                 const bf16* __restrict__ btIn,
                                                 const bf16* __restrict__ Wf,
                                                 const bf16* __restrict__ bias,
                                                 bf16* __restrict__ Y, int M,
                                                 float* __restrict__ ssum,
                                                 float* __restrict__ ssq) {
    const int K = 256, N = NF * 16;
    __shared__ float sscale[K], sshift[K];
    __shared__ float sred[2][4][N];
    for (int c = threadIdx.x; c < K; c += 256) {
        const float invM = 1.f / (float)NNODES;
        float mean = ssumIn[c] * invM;
        float var  = ssqIn[c] * invM - mean * mean;
        float a = b2f(gIn[c]) * rsqrtf(fmaxf(var, 0.f) + 1e-5f);
        sscale[c] = a;
        sshift[c] = b2f(btIn[c]) - mean * a;
    }
    __syncthreads();
    int lane = threadIdx.x & 63, wave = threadIdx.x >> 6;
    int rowbase = blockIdx.x * 64 + wave * 16;
    int arow = rowbase + (lane & 15);
    bool aval = (arow < M);
    int koff = (lane >> 4) << 3;
    size_t abase = (size_t)arow * K + koff;
    f32x4 acc[NF] = {};
#pragma unroll
    for (int ks = 0; ks < 8; ++ks) {
        bf16x8 a;
        if (aval) {
            bf16x8 raw = ld_frag(A + abase + ks * 32);
            int c0 = ks * 32 + koff;
#pragma unroll
            for (int j = 0; j < 8; ++j) {
                float v = bs2f(raw[j]) * sscale[c0 + j] + sshift[c0 + j];
                a[j] = f2bs(gelu_ex(v));
            }
        } else {
            a = zero8();
        }
#pragma unroll
        for (int f = 0; f < NF; ++f) {
            bf16x8 b = ld_frag(Wf + (((ks * NF + f) * 64 + lane) << 3));
            acc[f] = __builtin_amdgcn_mfma_f32_16x16x32_bf16(a, b, acc[f], 0, 0, 0);
        }
    }
    int hi = lane >> 4, coll = lane & 15;
    int crow = rowbase + hi * 4;
#pragma unroll
    for (int f = 0; f < NF; ++f) {
        int col = f * 16 + coll;
        float bv = b2f(bias[col]);
        float s = 0.f, q = 0.f;
#pragma unroll
        for (int r = 0; r < 4; ++r) {
            int row = crow + r;
            if (row < M) {
                float v = acc[f][r] + bv;
                Y[(size_t)row * N + col] = __float2bfloat16(v);
                s += v; q += v * v;
            }
        }
        s += __shfl_xor(s, 16); s += __shfl_xor(s, 32);
        q += __shfl_xor(q, 16); q += __shfl_xor(q, 32);
        if (hi == 0) { sred[0][wave][col] = s; sred[1][wave][col] = q; }
    }
    __syncthreads();
    for (int t = threadIdx.x; t < N; t += 256) {
        float s = sred[0][0][t] + sred[0][1][t] + sred[0][2][t] + sred[0][3][t];
        float q = sred[1][0][t] + sred[1][1][t] + sred[1][2][t] + sred[1][3][t];
        atomicAdd(&ssum[t], s); atomicAdd(&ssq[t], q);
    }
}

// ===== CSR node-parallel edge kernel: one wave per dst node, NO ATOMICS =====
// (round-13 proven version, byte-identical)
__global__ __launch_bounds__(64) void k_edge6(const bf16* __restrict__ eaP,
                                              const void* __restrict__ EA,
                                              const int* __restrict__ eids,
                                              const bf16* __restrict__ Wf,
                                              const bf16* __restrict__ bias,
                                              const int* __restrict__ srcs,
                                              const int* __restrict__ rowptr,
                                              const bf16* __restrict__ h,
                                              float* __restrict__ agg,
                                              const int* __restrict__ flags) {
    __shared__ short sm[16 * 132];
    bool f32 = (flags[0] == 0);
    int lane = threadIdx.x & 63;
    int d = blockIdx.x;
    int start = rowptr[d], end = rowptr[d + 1];
    int koff = (lane >> 4) << 3;
    int l2 = lane * 2;
    int hi = lane >> 4, coll = lane & 15;
    int rbase = hi * 4;
    float bx = b2f(bias[l2]), by = b2f(bias[l2 + 1]);
    float rx = 0.f, ry = 0.f;
    bool first = true;
    for (int c = start; c < end; c += 16) {
        int eidx = c + (lane & 15);
        int ok_l = (eidx < end) ? 1 : 0;
        int sc_l = ok_l ? srcs[eidx] : 0;
        f32x4 acc[8] = {};
        if (eaP) {
            const bf16* ap = eaP + (size_t)eidx * 64 + koff;
#pragma unroll
            for (int ks = 0; ks < 2; ++ks) {
                bf16x8 a = ok_l ? ld_frag(ap + ks * 32) : zero8();
#pragma unroll
                for (int f = 0; f < 8; ++f) {
                    bf16x8 b = ld_frag(Wf + (((ks * 8 + f) * 64 + lane) << 3));
                    acc[f] = __builtin_amdgcn_mfma_f32_16x16x32_bf16(a, b, acc[f], 0, 0, 0);
                }
            }
        } else {
            size_t abase = ok_l ? ((size_t)eids[eidx] * 64 + koff) : 0;
#pragma unroll
            for (int ks = 0; ks < 2; ++ks) {
                bf16x8 a = ok_l ? ld_a8(EA, abase + ks * 32, f32) : zero8();
#pragma unroll
                for (int f = 0; f < 8; ++f) {
                    bf16x8 b = ld_frag(Wf + (((ks * 8 + f) * 64 + lane) << 3));
                    acc[f] = __builtin_amdgcn_mfma_f32_16x16x32_bf16(a, b, acc[f], 0, 0, 0);
                }
            }
        }
        unsigned hv[16];
#pragma unroll
        for (int e = 0; e < 16; ++e) {
            int s = __shfl(sc_l, e);
            hv[e] = *reinterpret_cast<const unsigned*>(
                reinterpret_cast<const unsigned short*>(h) + (size_t)s * 128 + l2);
        }
        if (!first) __syncthreads();
        first = false;
#pragma unroll
        for (int f = 0; f < 8; ++f)
#pragma unroll
            for (int r = 0; r < 4; ++r)
                sm[(rbase + r) * 132 + f * 16 + coll] = f2bs(acc[f][r]);
        __syncthreads();
        int lim = end - c; if (lim > 16) lim = 16;
        for (int e = 0; e < lim; ++e) {
            unsigned mu = *reinterpret_cast<const unsigned*>(&sm[e * 132 + l2]);
            float vx = u2f_lo(mu) + u2f_lo(hv[e]) + bx;
            float vy = u2f_hi(mu) + u2f_hi(hv[e]) + by;
            rx += fmaxf(vx, 0.f); ry += fmaxf(vy, 0.f);
        }
    }
    agg[(size_t)d * 128 + l2]     = rx;
    agg[(size_t)d * 128 + l2 + 1] = ry;
}

// ===== k_edge6b: low-VGPR variant (A/B on layer 1) — acc split in halves, hv via LDS.
// Single-wave block: all LDS ops program-ordered; barriers are mere fences.
__global__ __launch_bounds__(64, 8) void k_edge6b(const bf16* __restrict__ eaP,
                                                  const void* __restrict__ EA,
                                                  const int* __restrict__ eids,
                                                  const bf16* __restrict__ Wf,
                                                  const bf16* __restrict__ bias,
                                                  const int* __restrict__ srcs,
                                                  const int* __restrict__ rowptr,
                                                  const bf16* __restrict__ h,
                                                  float* __restrict__ agg,
                                                  const int* __restrict__ flags) {
    __shared__ short sm[16 * 132];
    __shared__ unsigned hbuf[16 * 64];
    bool f32 = (flags[0] == 0);
    int lane = threadIdx.x & 63;
    int d = blockIdx.x;
    int start = rowptr[d], end = rowptr[d + 1];
    int koff = (lane >> 4) << 3;
    int l2 = lane * 2;
    int hi = lane >> 4, coll = lane & 15;
    int rbase = hi * 4;
    float bx = b2f(bias[l2]), by = b2f(bias[l2 + 1]);
    float rx = 0.f, ry = 0.f;
    bool first = true;
    for (int c = start; c < end; c += 16) {
        int eidx = c + (lane & 15);
        int ok_l = (eidx < end) ? 1 : 0;
        int sc_l = ok_l ? srcs[eidx] : 0;
        // load A fragments once (reused by both halves)
        bf16x8 a0, a1;
        if (eaP) {
            const bf16* ap = eaP + (size_t)eidx * 64 + koff;
            a0 = ok_l ? ld_frag(ap)      : zero8();
            a1 = ok_l ? ld_frag(ap + 32) : zero8();
        } else {
            size_t abase = ok_l ? ((size_t)eids[eidx] * 64 + koff) : 0;
            a0 = ok_l ? ld_a8(EA, abase, f32)      : zero8();
            a1 = ok_l ? ld_a8(EA, abase + 32, f32) : zero8();
        }
        if (!first) __syncthreads();
        first = false;
        // half 0: fragments 0..3 -> sm cols 0..63
        {
            f32x4 acc[4] = {};
#pragma unroll
            for (int j = 0; j < 4; ++j) {
                acc[j] = __builtin_amdgcn_mfma_f32_16x16x32_bf16(
                    a0, ld_frag(Wf + (((0 * 8 + j) * 64 + lane) << 3)), acc[j], 0, 0, 0);
                acc[j] = __builtin_amdgcn_mfma_f32_16x16x32_bf16(
                    a1, ld_frag(Wf + (((1 * 8 + j) * 64 + lane) << 3)), acc[j], 0, 0, 0);
            }
#pragma unroll
            for (int j = 0; j < 4; ++j)
#pragma unroll
                for (int r = 0; r < 4; ++r)
                    sm[(rbase + r) * 132 + j * 16 + coll] = f2bs(acc[j][r]);
        }
        // half 1: fragments 4..7 -> sm cols 64..127
        {
            f32x4 acc[4] = {};
#pragma unroll
            for (int j = 0; j < 4; ++j) {
                acc[j] = __builtin_amdgcn_mfma_f32_16x16x32_bf16(
                    a0, ld_frag(Wf + (((0 * 8 + 4 + j) * 64 + lane) << 3)), acc[j], 0, 0, 0);
                acc[j] = __builtin_amdgcn_mfma_f32_16x16x32_bf16(
                    a1, ld_frag(Wf + (((1 * 8 + 4 + j) * 64 + lane) << 3)), acc[j], 0, 0, 0);
            }
#pragma unroll
            for (int j = 0; j < 4; ++j)
#pragma unroll
                for (int r = 0; r < 4; ++r)
                    sm[(rbase + r) * 132 + (4 + j) * 16 + coll] = f2bs(acc[j][r]);
        }
        // h prefetch through LDS (no 16-register residency)
#pragma unroll
        for (int e = 0; e < 16; ++e) {
            int s = __shfl(sc_l, e);
            hbuf[e * 64 + lane] = *reinterpret_cast<const unsigned*>(
                reinterpret_cast<const unsigned short*>(h) + (size_t)s * 128 + l2);
        }
        __syncthreads();
        int lim = end - c; if (lim > 16) lim = 16;
        for (int e = 0; e < lim; ++e) {
            unsigned mu = *reinterpret_cast<const unsigned*>(&sm[e * 132 + l2]);
            unsigned hu = hbuf[e * 64 + lane];
            float vx = u2f_lo(mu) + u2f_lo(hu) + bx;
            float vy = u2f_hi(mu) + u2f_hi(hu) + by;
            rx += fmaxf(vx, 0.f); ry += fmaxf(vy, 0.f);
        }
    }
    agg[(size_t)d * 128 + l2]     = rx;
    agg[(size_t)d * 128 + l2 + 1] = ry;
}

// ---------- legacy unsorted edge kernel (tier C fallback)
__global__ __launch_bounds__(256) void k_edge(const void* __restrict__ EA,
                                              const bf16* __restrict__ Wf,
                                              const bf16* __restrict__ bias,
                                              const void* __restrict__ ei,
                                              const bf16* __restrict__ h,
                                              float* __restrict__ agg,
                                              const int* __restrict__ flags) {
    bool f32 = (flags[0] == 0);
    bool i64 = (flags[1] == 1);
    const int K = 64, NF = 8;
    int lane = threadIdx.x & 63, wave = threadIdx.x >> 6;
    int rowbase = blockIdx.x * 64 + wave * 16;
    int colbase = blockIdx.y * 64;
    int arow = rowbase + (lane & 15);
    size_t abase = (size_t)arow * K + ((lane >> 4) << 3);
    f32x4 acc[4] = {};
#pragma unroll
    for (int ks = 0; ks < 2; ++ks) {
        bf16x8 a = ld_a8(EA, abase + ks * 32, f32);
#pragma unroll
        for (int f = 0; f < 4; ++f) {
            bf16x8 b = ld_frag(Wf + (((ks * NF + colbase / 16 + f) * 64 + lane) << 3));
            acc[f] = __builtin_amdgcn_mfma_f32_16x16x32_bf16(a, b, acc[f], 0, 0, 0);
        }
    }
    int erow = rowbase + ((lane >> 4) << 2);
    int coll = lane & 15;
    float bv[4];
#pragma unroll
    for (int f = 0; f < 4; ++f) bv[f] = b2f(bias[colbase + f * 16 + coll]);
#pragma unroll
    for (int r = 0; r < 4; ++r) {
        int e = erow + r;
        int s, d;
        if (i64) {
            s = (int)((const long long*)ei)[e];
            d = (int)((const long long*)ei)[NEDGES + e];
        } else {
            s = ((const int*)ei)[e];
            d = ((const int*)ei)[NEDGES + e];
        }
        if ((unsigned)s >= NNODES || (unsigned)d >= NNODES) continue;
        const bf16* hp = h + (size_t)s * HIDDEN;
        float* gp = agg + (size_t)d * HIDDEN;
#pragma unroll
        for (int f = 0; f < 4; ++f) {
            int col = colbase + f * 16 + coll;
            float v = acc[f][r] + bv[f] + b2f(hp[col]);
            if (v > 0.f) atomicAdd(gp + col, v);
        }
    }
}

// ---------- fused BN-finalize + normalize + exact GELU (x4) + optional agg-zero tail
template<int N>
__global__ void k_bngelu4(const bf16* __restrict__ y, const float* __restrict__ ssum,
                          const float* __restrict__ ssq, const bf16* __restrict__ g,
                          const bf16* __restrict__ beta, bf16* __restrict__ z,
                          void* __restrict__ out_base, int slice,
                          const int* __restrict__ flags,
                          float* __restrict__ aggz, int aggn4) {
    __shared__ float sscale[N], sshift[N];
    for (int c = threadIdx.x; c < N; c += 256) {
        const float invM = 1.f / (float)NNODES;
        float mean = ssum[c] * invM;
        float var  = ssq[c] * invM - mean * mean;
        float a = b2f(g[c]) * rsqrtf(fmaxf(var, 0.f) + 1e-5f);
        sscale[c] = a;
        sshift[c] = b2f(beta[c]) - mean * a;
    }
    __syncthreads();
    bool outb = (flags[0] == 1);
    const int total4 = NNODES * N / 4;
    for (int i4 = blockIdx.x * 256 + threadIdx.x; i4 < total4; i4 += gridDim.x * 256) {
        int i = i4 * 4;
        int col = i & (N - 1);
        ushort4 yv = ((const ushort4*)y)[i4];
        float g0 = gelu_ex(u2f_lo(yv.x) * sscale[col]     + sshift[col]);
        float g1 = gelu_ex(u2f_lo(yv.y) * sscale[col + 1] + sshift[col + 1]);
        float g2 = gelu_ex(u2f_lo(yv.z) * sscale[col + 2] + sshift[col + 2]);
        float g3 = gelu_ex(u2f_lo(yv.w) * sscale[col + 3] + sshift[col + 3]);
        ushort4 zv;
        zv.x = (unsigned short)f2bs(g0); zv.y = (unsigned short)f2bs(g1);
        zv.z = (unsigned short)f2bs(g2); zv.w = (unsigned short)f2bs(g3);
        ((ushort4*)z)[i4] = zv;
        if (slice >= 0) {
            int row = i / N;
            size_t ob = (size_t)row * 512 + (size_t)slice * 128 + col;
            if (outb) {
                *reinterpret_cast<ushort4*>((unsigned short*)out_base + ob) = zv;
            } else {
                float4 gv = {g0, g1, g2, g3};
                *reinterpret_cast<float4*>((float*)out_base + ob) = gv;
            }
        }
    }
    if (aggz) {
        float4 zzz = {0.f, 0.f, 0.f, 0.f};
        for (int i4 = blockIdx.x * 256 + threadIdx.x; i4 < aggn4; i4 += gridDim.x * 256)
            ((float4*)aggz)[i4] = zzz;
    }
}

extern "C" void kernel_launch(void* const* d_in, const int* in_sizes, int n_in,
                              void* d_out, int out_size, void* d_ws, size_t ws_size,
                              hipStream_t stream) {
    const void* x      = d_in[0];
    const void* ei     = d_in[1];
    const void* ea     = d_in[2];
    const void* emb_w  = d_in[3];
    const void* emb_b  = d_in[4];
    const void* emb_g  = d_in[5];
    const void* emb_bt = d_in[6];
    const void* eps    = d_in[7];
    const void* lin_w  = d_in[8];
    const void* lin_b  = d_in[9];
    const void* w1     = d_in[10];
    const void* b1     = d_in[11];
    const void* g1     = d_in[12];
    const void* bt1    = d_in[13];
    const void* w2     = d_in[14];
    const void* b2     = d_in[15];
    const void* g2     = d_in[16];
    const void* bt2    = d_in[17];

    char* ws = (char*)d_ws;
    int*   flags  = (int*)ws;
    float* stats  = (float*)(ws + 1024);
    bf16*  canon  = (bf16*)(ws + 16384);
    bf16*  wf0    = (bf16*)(ws + 32768);
    bf16*  lin_wf = wf0 + 16384;
    bf16*  w1f    = wf0 + 40960;
    bf16*  w2f    = wf0 + 139264;
    bf16*  bufH   = (bf16*)(ws + 524288);       // [50000,128] bf16 (y0 / h)
    bf16*  bufA   = (bf16*)(ws + 13324288);     // [50000,128] bf16 (y2)
    char*  bufC   = (ws + 26124288);            // 25.6 MB (agg fp32 | y1 bf16)
    float* aggf   = (float*)bufC;
    bf16*  y1     = (bf16*)bufC;
    const size_t SB = 51724288;
    int*  rowptr  = (int*)(ws + SB);
    int*  cursorA = (int*)(ws + SB + 200704);
    int*  srcs    = (int*)(ws + SB + 401408);
    int*  dsts    = (int*)(ws + SB + 3601408);
    int*  eids    = (int*)(ws + SB + 6801408);
    bf16* eaP     = (bf16*)(ws + SB + 10001408);
    int*  cursorB = (int*)bufA;                       // dead region during sort phase
    int*  pos_of  = (int*)(ws + 13324288 + 1048576);  // bufA+1MB, dead during sort phase
    const unsigned long long TIERA_NEED = SB + 10001408ull + 102400000ull;
    const unsigned long long TIERB_NEED = SB + 10001408ull;
    bool tierA = ws_size >= TIERA_NEED;
    bool tierB = !tierA && ws_size >= TIERB_NEED;
    bool sorted = tierA || tierB;
    const int AGGN4 = NNODES * HIDDEN / 4;

    k_init<<<256, 256, 0, stream>>>(stats, cursorA, cursorB, sorted ? 1 : 0);
    k_detect_cvt<<<1, 256, 0, stream>>>((const unsigned*)emb_g, (const unsigned*)ei, flags,
                                        emb_b, emb_g, emb_bt, eps, lin_b, b1, g1, bt1,
                                        b2, g2, bt2, canon);
    k_repack_all<<<928, 256, 0, stream>>>(emb_w, lin_w, w1, w2, wf0, flags);

    if (sorted) {
        k_hist<<<1024, 256, 0, stream>>>(ei, cursorA, flags);
        k_scan<<<1, 1024, 0, stream>>>(cursorA, rowptr);
        k_scatter<<<1024, 256, 0, stream>>>(ei, rowptr, cursorB, srcs, dsts, eids,
                                            pos_of, flags);
        if (tierA) k_permEA3<<<6250, 256, 0, stream>>>(ea, pos_of, eaP, flags);
    }

    // ---- node embed (stats slot 0); tier-C needs agg pre-zeroed via bngelu tail
    float* aggz0 = sorted ? (float*)nullptr : aggf;
    k_gemm<128, 8><<<782, 256, 0, stream>>>(x, wf0, canon + C_EMB_B, bufH, NNODES,
                                            stats, stats + 256, flags, 1);
    k_bngelu4<128><<<2048, 256, 0, stream>>>(bufH, stats, stats + 256,
                                             canon + C_EMB_G, canon + C_EMB_BT,
                                             bufH, d_out, 0, flags, aggz0, AGGN4);

    for (int i = 0; i < 3; ++i) {
        float* s1 = stats + (size_t)(1 + 2 * i) * 512;
        float* s2 = stats + (size_t)(2 + 2 * i) * 512;
        if (sorted) {
            const bf16* pA = tierA ? eaP : (const bf16*)nullptr;
            const void* pE = tierA ? (const void*)nullptr : ea;
            const int*  pI = tierA ? (const int*)nullptr : eids;
            if (i == 1)   // within-run A/B: low-VGPR variant on layer 1
                k_edge6b<<<NNODES, 64, 0, stream>>>(pA, pE, pI,
                                                    lin_wf + i * 8192,
                                                    canon + C_LIN_B + i * 128,
                                                    srcs, rowptr, bufH, aggf, flags);
            else
                k_edge6<<<NNODES, 64, 0, stream>>>(pA, pE, pI,
                                                   lin_wf + i * 8192,
                                                   canon + C_LIN_B + i * 128,
                                                   srcs, rowptr, bufH, aggf, flags);
        } else {
            k_edge<<<dim3(12500, 2), 256, 0, stream>>>(ea, lin_wf + i * 8192,
                                                       canon + C_LIN_B + i * 128, ei,
                                                       bufH, aggf, flags);
        }
        // MLP layer 1 with fused zin (stats slot 1+2i); y1 = raw pre-BN output
        k_gemm_zin<16><<<782, 256, 0, stream>>>(bufH, aggf, canon + C_EPS, i,
                                                w1f + i * 32768, canon + C_B1 + i * 256,
                                                y1, NNODES, s1, s1 + 256);
        // MLP layer 2 with consumer-fused BN+GELU on y1 (stats slot 2+2i)
        k_gemm_bn<8><<<782, 256, 0, stream>>>(y1, s1, s1 + 256, canon + C_G1 + i * 256,
                                              canon + C_BT1 + i * 256,
                                              w2f + i * 32768, canon + C_B2 + i * 128,
                                              bufA, NNODES, s2, s2 + 256);
        // slice bngelu; tier-C zero-tail for next layer's atomics (sorted path: none)
        float* aggz = (!sorted && i < 2) ? aggf : (float*)nullptr;
        k_bngelu4<128><<<2048, 256, 0, stream>>>(bufA, s2, s2 + 256, canon + C_G2 + i * 128,
                                                 canon + C_BT2 + i * 128, bufH, d_out,
                                                 i + 1, flags, aggz, AGGN4);
    }
}

// Round 16
// 831.210 us; speedup vs baseline: 1.2123x; 1.0765x over previous
//
#include <hip/hip_runtime.h>
#include <hip/hip_bf16.h>

typedef __hip_bfloat16 bf16;
typedef __attribute__((ext_vector_type(8))) short bf16x8;
typedef __attribute__((ext_vector_type(4))) float f32x4;

#define HIDDEN 128
#define NNODES 50000
#define NEDGES 800000

static __device__ __forceinline__ float b2f(bf16 v) { return __bfloat162float(v); }
static __device__ __forceinline__ short f2bs(float f) {
    bf16 b = __float2bfloat16(f);
    return *reinterpret_cast<const short*>(&b);
}
static __device__ __forceinline__ float bs2f(short s) {
    unsigned x = ((unsigned)(unsigned short)s) << 16;
    return *reinterpret_cast<const float*>(&x);
}
static __device__ __forceinline__ bf16x8 ld_frag(const bf16* p) {
    return *reinterpret_cast<const bf16x8*>(p);
}
static __device__ __forceinline__ bf16x8 zero8() {
    bf16x8 z = {0, 0, 0, 0, 0, 0, 0, 0};
    return z;
}
static __device__ __forceinline__ float u2f_lo(unsigned u) {
    unsigned x = u << 16; return *reinterpret_cast<const float*>(&x);
}
static __device__ __forceinline__ float u2f_hi(unsigned u) {
    unsigned x = u & 0xffff0000u; return *reinterpret_cast<const float*>(&x);
}
static __device__ __forceinline__ bf16x8 ld_a8(const void* base, size_t off, bool f32) {
    if (!f32) return *reinterpret_cast<const bf16x8*>((const bf16*)base + off);
    const float4* p = reinterpret_cast<const float4*>((const float*)base + off);
    float4 u = p[0], w = p[1];
    bf16x8 r;
    r[0]=f2bs(u.x); r[1]=f2bs(u.y); r[2]=f2bs(u.z); r[3]=f2bs(u.w);
    r[4]=f2bs(w.x); r[5]=f2bs(w.y); r[6]=f2bs(w.z); r[7]=f2bs(w.w);
    return r;
}
static __device__ __forceinline__ float gelu_ex(float v) {
    return 0.5f * v * (1.f + erff(v * 0.70710678118654752f));
}

#define C_EMB_B   0
#define C_EMB_G   128
#define C_EMB_BT  256
#define C_EPS     384
#define C_LIN_B   400
#define C_B1      800
#define C_G1      1568
#define C_BT1     2336
#define C_B2      3104
#define C_G2      3488
#define C_BT2     3872

__global__ void k_init(float* __restrict__ stats, int* __restrict__ cursorA,
                       int* __restrict__ cursorB, int doSort) {
    int tid = blockIdx.x * 256 + threadIdx.x;
    int stride = gridDim.x * 256;
    for (int i = tid; i < 3584; i += stride) stats[i] = 0.f;
    if (doSort) for (int i = tid; i < NNODES; i += stride) cursorA[i] = 0;
    for (int i = tid; i < NNODES; i += stride) cursorB[i] = 0;
}

__global__ void k_detect_cvt(const unsigned* __restrict__ gones,
                             const unsigned* __restrict__ eiw, int* __restrict__ flags,
                             const void* emb_b, const void* emb_g, const void* emb_bt,
                             const void* eps, const void* lin_b, const void* b1,
                             const void* g1, const void* bt1, const void* b2,
                             const void* g2, const void* bt2, bf16* __restrict__ canon) {
    __shared__ int sf;
    if (threadIdx.x == 0) {
        int f0 = (gones[0] == 0x3F803F80u) ? 1 : 0;
        unsigned s = 0;
        for (int i = 1; i < 64; i += 2) s |= eiw[i];
        flags[0] = f0; flags[1] = (s == 0u) ? 1 : 0;
        sf = f0;
    }
    __syncthreads();
    bool f32 = (sf == 0);
    const void* ps[11] = {emb_b, emb_g, emb_bt, eps, lin_b, b1, g1, bt1, b2, g2, bt2};
    const int   ns[11] = {128, 128, 128, 3, 384, 768, 768, 768, 384, 384, 384};
    const int   os[11] = {C_EMB_B, C_EMB_G, C_EMB_BT, C_EPS, C_LIN_B, C_B1,
                          C_G1, C_BT1, C_B2, C_G2, C_BT2};
    for (int seg = 0; seg < 11; ++seg)
        for (int i = threadIdx.x; i < ns[seg]; i += 256) {
            short v = f32 ? f2bs(((const float*)ps[seg])[i]) : ((const short*)ps[seg])[i];
            ((short*)canon)[os[seg] + i] = v;
        }
}

__global__ void k_repack_all(const void* __restrict__ emb_w, const void* __restrict__ lin_w,
                             const void* __restrict__ w1, const void* __restrict__ w2,
                             bf16* __restrict__ Wf, const int* __restrict__ flags) {
    const int starts[11] = {0, 16384, 24576, 32768, 40960, 73728, 106496,
                            139264, 172032, 204800, 237568};
    int idx = blockIdx.x * 256 + threadIdx.x;
    if (idx >= 237568) return;
    bool f32 = (flags[0] == 0);
    int seg = 0;
    while (idx >= starts[seg + 1]) ++seg;
    int local = idx - starts[seg];
    const void* base; long long eoff; int K, N;
    if (seg == 0)      { base = emb_w; eoff = 0;                          K = 128; N = 128; }
    else if (seg <= 3) { base = lin_w; eoff = (long long)(seg - 1) * 8192;  K = 64;  N = 128; }
    else if (seg <= 6) { base = w1;    eoff = (long long)(seg - 4) * 32768; K = 128; N = 256; }
    else               { base = w2;    eoff = (long long)(seg - 7) * 32768; K = 256; N = 128; }
    int j    = local & 7;
    int lane = (local >> 3) & 63;
    int rest = local >> 9;
    int NF   = N >> 4;
    int ks   = rest / NF;
    int nf   = rest - ks * NF;
    int k = ks * 32 + ((lane >> 4) << 3) + j;
    int n = (nf << 4) + (lane & 15);
    long long src = eoff + (long long)k * N + n;
    short v = f32 ? f2bs(((const float*)base)[src]) : ((const short*)base)[src];
    ((short*)Wf)[idx] = v;
}

// ================= sort by dst (counting sort) =================
__global__ void k_hist(const void* __restrict__ ei, int* __restrict__ deg,
                       const int* __restrict__ flags) {
    bool i64 = (flags[1] == 1);
    for (int e = blockIdx.x * 256 + threadIdx.x; e < NEDGES; e += gridDim.x * 256) {
        int d = i64 ? (int)((const long long*)ei)[NEDGES + e] : ((const int*)ei)[NEDGES + e];
        if ((unsigned)d < NNODES) atomicAdd(&deg[d], 1);
    }
}

__global__ __launch_bounds__(1024) void k_scan(const int* __restrict__ deg,
                                               int* __restrict__ rowptr) {
    __shared__ int part[1024];
    const int CH = 49;
    int t = threadIdx.x;
    int lo = t * CH, hi = lo + CH; if (hi > NNODES) hi = NNODES; if (lo > NNODES) lo = NNODES;
    int s = 0;
    for (int i = lo; i < hi; ++i) s += deg[i];
    part[t] = s;
    __syncthreads();
    for (int off = 1; off < 1024; off <<= 1) {
        int v = (t >= off) ? part[t - off] : 0;
        __syncthreads();
        part[t] += v;
        __syncthreads();
    }
    int run = (t == 0) ? 0 : part[t - 1];
    for (int i = lo; i < hi; ++i) { rowptr[i] = run; run += deg[i]; }
    if (t == 1023) rowptr[NNODES] = run;
}

__global__ void k_scatter(const void* __restrict__ ei, const int* __restrict__ rowptr,
                          int* __restrict__ cursor, int* __restrict__ srcs,
                          int* __restrict__ dsts, int* __restrict__ eids,
                          int* __restrict__ pos_of,
                          const int* __restrict__ flags) {
    bool i64 = (flags[1] == 1);
    for (int e = blockIdx.x * 256 + threadIdx.x; e < NEDGES; e += gridDim.x * 256) {
        int s, d;
        if (i64) {
            s = (int)((const long long*)ei)[e];
            d = (int)((const long long*)ei)[NEDGES + e];
        } else {
            s = ((const int*)ei)[e];
            d = ((const int*)ei)[NEDGES + e];
        }
        if ((unsigned)s >= NNODES || (unsigned)d >= NNODES) { pos_of[e] = -1; continue; }
        int pos = rowptr[d] + atomicAdd(&cursor[d], 1);
        srcs[pos] = s; dsts[pos] = d; eids[pos] = e; pos_of[e] = pos;
    }
}

// ---------- permute-gather of edge_attr, LINEAR coalesced read / random row write
__global__ void k_permEA3(const void* __restrict__ EA, const int* __restrict__ pos_of,
                          bf16* __restrict__ eaP, const int* __restrict__ flags) {
    bool f32 = (flags[0] == 0);
    int tid = blockIdx.x * 256 + threadIdx.x;
    int t = tid & 7;
    int r0 = (tid >> 3) * 4;
    if (r0 >= NEDGES) return;
    int p[4];
#pragma unroll
    for (int j = 0; j < 4; ++j) p[j] = pos_of[r0 + j];
    if (f32) {
        float4 a[4], b[4];
#pragma unroll
        for (int j = 0; j < 4; ++j) {
            const float4* q = reinterpret_cast<const float4*>(
                (const float*)EA + (size_t)(r0 + j) * 64 + t * 8);
            a[j] = q[0]; b[j] = q[1];
        }
#pragma unroll
        for (int j = 0; j < 4; ++j) {
            if (p[j] < 0) continue;
            bf16x8 r;
            r[0]=f2bs(a[j].x); r[1]=f2bs(a[j].y); r[2]=f2bs(a[j].z); r[3]=f2bs(a[j].w);
            r[4]=f2bs(b[j].x); r[5]=f2bs(b[j].y); r[6]=f2bs(b[j].z); r[7]=f2bs(b[j].w);
            *reinterpret_cast<bf16x8*>(eaP + (size_t)p[j] * 64 + t * 8) = r;
        }
    } else {
        bf16x8 a[4];
#pragma unroll
        for (int j = 0; j < 4; ++j)
            a[j] = *reinterpret_cast<const bf16x8*>(
                (const bf16*)EA + (size_t)(r0 + j) * 64 + t * 8);
#pragma unroll
        for (int j = 0; j < 4; ++j) {
            if (p[j] < 0) continue;
            *reinterpret_cast<bf16x8*>(eaP + (size_t)p[j] * 64 + t * 8) = a[j];
        }
    }
}

// ================= GEMM with fused bias + BN column stats =================
template<int K, int NF>
__global__ __launch_bounds__(256) void k_gemm(const void* __restrict__ A,
                                              const bf16* __restrict__ Wf,
                                              const bf16* __restrict__ bias,
                                              bf16* __restrict__ Y, int M,
                                              float* __restrict__ ssum,
                                              float* __restrict__ ssq,
                                              const int* __restrict__ flags, int flexA) {
    const int N = NF * 16;
    __shared__ float sred[2][4][N];
    bool f32 = flexA && (flags[0] == 0);
    int lane = threadIdx.x & 63, wave = threadIdx.x >> 6;
    int rowbase = blockIdx.x * 64 + wave * 16;
    int arow = rowbase + (lane & 15);
    bool aval = (arow < M);
    size_t abase = (size_t)arow * K + ((lane >> 4) << 3);
    f32x4 acc[NF] = {};
#pragma unroll
    for (int ks = 0; ks < K / 32; ++ks) {
        bf16x8 a = aval ? ld_a8(A, abase + ks * 32, f32) : zero8();
#pragma unroll
        for (int f = 0; f < NF; ++f) {
            bf16x8 b = ld_frag(Wf + (((ks * NF + f) * 64 + lane) << 3));
            acc[f] = __builtin_amdgcn_mfma_f32_16x16x32_bf16(a, b, acc[f], 0, 0, 0);
        }
    }
    int hi = lane >> 4, coll = lane & 15;
    int crow = rowbase + hi * 4;
#pragma unroll
    for (int f = 0; f < NF; ++f) {
        int col = f * 16 + coll;
        float bv = b2f(bias[col]);
        float s = 0.f, q = 0.f;
#pragma unroll
        for (int r = 0; r < 4; ++r) {
            int row = crow + r;
            if (row < M) {
                float v = acc[f][r] + bv;
                Y[(size_t)row * N + col] = __float2bfloat16(v);
                s += v; q += v * v;
            }
        }
        s += __shfl_xor(s, 16); s += __shfl_xor(s, 32);
        q += __shfl_xor(q, 16); q += __shfl_xor(q, 32);
        if (hi == 0) { sred[0][wave][col] = s; sred[1][wave][col] = q; }
    }
    __syncthreads();
    for (int t = threadIdx.x; t < N; t += 256) {
        float s = sred[0][0][t] + sred[0][1][t] + sred[0][2][t] + sred[0][3][t];
        float q = sred[1][0][t] + sred[1][1][t] + sred[1][2][t] + sred[1][3][t];
        atomicAdd(&ssum[t], s); atomicAdd(&ssq[t], q);
    }
}

// ======= GEMM with fused zin input (A = bf16((1+eps)h + agg)), K=128 =======
template<int NF>
__global__ __launch_bounds__(256) void k_gemm_zin(const bf16* __restrict__ h,
                                                  const float* __restrict__ agg,
                                                  const bf16* __restrict__ epsc, int layer,
                                                  const bf16* __restrict__ Wf,
                                                  const bf16* __restrict__ bias,
                                                  bf16* __restrict__ Y, int M,
                                                  float* __restrict__ ssum,
                                                  float* __restrict__ ssq) {
    const int K = 128, N = NF * 16;
    __shared__ float sred[2][4][N];
    float e1 = 1.f + b2f(epsc[layer]);
    int lane = threadIdx.x & 63, wave = threadIdx.x >> 6;
    int rowbase = blockIdx.x * 64 + wave * 16;
    int arow = rowbase + (lane & 15);
    bool aval = (arow < M);
    size_t abase = (size_t)arow * K + ((lane >> 4) << 3);
    f32x4 acc[NF] = {};
#pragma unroll
    for (int ks = 0; ks < 4; ++ks) {
        bf16x8 a;
        if (aval) {
            size_t off = abase + ks * 32;
            bf16x8 hv = ld_frag(h + off);
            float4 a0 = *reinterpret_cast<const float4*>(agg + off);
            float4 a1 = *reinterpret_cast<const float4*>(agg + off + 4);
            a[0] = f2bs(e1 * bs2f(hv[0]) + a0.x);
            a[1] = f2bs(e1 * bs2f(hv[1]) + a0.y);
            a[2] = f2bs(e1 * bs2f(hv[2]) + a0.z);
            a[3] = f2bs(e1 * bs2f(hv[3]) + a0.w);
            a[4] = f2bs(e1 * bs2f(hv[4]) + a1.x);
            a[5] = f2bs(e1 * bs2f(hv[5]) + a1.y);
            a[6] = f2bs(e1 * bs2f(hv[6]) + a1.z);
            a[7] = f2bs(e1 * bs2f(hv[7]) + a1.w);
        } else {
            a = zero8();
        }
#pragma unroll
        for (int f = 0; f < NF; ++f) {
            bf16x8 b = ld_frag(Wf + (((ks * NF + f) * 64 + lane) << 3));
            acc[f] = __builtin_amdgcn_mfma_f32_16x16x32_bf16(a, b, acc[f], 0, 0, 0);
        }
    }
    int hi = lane >> 4, coll = lane & 15;
    int crow = rowbase + hi * 4;
#pragma unroll
    for (int f = 0; f < NF; ++f) {
        int col = f * 16 + coll;
        float bv = b2f(bias[col]);
        float s = 0.f, q = 0.f;
#pragma unroll
        for (int r = 0; r < 4; ++r) {
            int row = crow + r;
            if (row < M) {
                float v = acc[f][r] + bv;
                Y[(size_t)row * N + col] = __float2bfloat16(v);
                s += v; q += v * v;
            }
        }
        s += __shfl_xor(s, 16); s += __shfl_xor(s, 32);
        q += __shfl_xor(q, 16); q += __shfl_xor(q, 32);
        if (hi == 0) { sred[0][wave][col] = s; sred[1][wave][col] = q; }
    }
    __syncthreads();
    for (int t = threadIdx.x; t < N; t += 256) {
        float s = sred[0][0][t] + sred[0][1][t] + sred[0][2][t] + sred[0][3][t];
        float q = sred[1][0][t] + sred[1][1][t] + sred[1][2][t] + sred[1][3][t];
        atomicAdd(&ssum[t], s); atomicAdd(&ssq[t], q);
    }
}

// ======= GEMM with fused BN+GELU on A (A = gelu(bn(y1raw))), K=256 =======
template<int NF>
__global__ __launch_bounds__(256) void k_gemm_bn(const bf16* __restrict__ A,
                                                 const float* __restrict__ ssumIn,
                                                 const float* __restrict__ ssqIn,
                                                 const bf16* __restrict__ gIn,
                                                 const bf16* __restrict__ btIn,
                                                 const bf16* __restrict__ Wf,
                                                 const bf16* __restrict__ bias,
                                                 bf16* __restrict__ Y, int M,
                                                 float* __restrict__ ssum,
                                                 float* __restrict__ ssq) {
    const int K = 256, N = NF * 16;
    __shared__ float sscale[K], sshift[K];
    __shared__ float sred[2][4][N];
    for (int c = threadIdx.x; c < K; c += 256) {
        const float invM = 1.f / (float)NNODES;
        float mean = ssumIn[c] * invM;
        float var  = ssqIn[c] * invM - mean * mean;
        float a = b2f(gIn[c]) * rsqrtf(fmaxf(var, 0.f) + 1e-5f);
        sscale[c] = a;
        sshift[c] = b2f(btIn[c]) - mean * a;
    }
    __syncthreads();
    int lane = threadIdx.x & 63, wave = threadIdx.x >> 6;
    int rowbase = blockIdx.x * 64 + wave * 16;
    int arow = rowbase + (lane & 15);
    bool aval = (arow < M);
    int koff = (lane >> 4) << 3;
    size_t abase = (size_t)arow * K + koff;
    f32x4 acc[NF] = {};
#pragma unroll
    for (int ks = 0; ks < 8; ++ks) {
        bf16x8 a;
        if (aval) {
            bf16x8 raw = ld_frag(A + abase + ks * 32);
            int c0 = ks * 32 + koff;
#pragma unroll
            for (int j = 0; j < 8; ++j) {
                float v = bs2f(raw[j]) * sscale[c0 + j] + sshift[c0 + j];
                a[j] = f2bs(gelu_ex(v));
            }
        } else {
            a = zero8();
        }
#pragma unroll
        for (int f = 0; f < NF; ++f) {
            bf16x8 b = ld_frag(Wf + (((ks * NF + f) * 64 + lane) << 3));
            acc[f] = __builtin_amdgcn_mfma_f32_16x16x32_bf16(a, b, acc[f], 0, 0, 0);
        }
    }
    int hi = lane >> 4, coll = lane & 15;
    int crow = rowbase + hi * 4;
#pragma unroll
    for (int f = 0; f < NF; ++f) {
        int col = f * 16 + coll;
        float bv = b2f(bias[col]);
        float s = 0.f, q = 0.f;
#pragma unroll
        for (int r = 0; r < 4; ++r) {
            int row = crow + r;
            if (row < M) {
                float v = acc[f][r] + bv;
                Y[(size_t)row * N + col] = __float2bfloat16(v);
                s += v; q += v * v;
            }
        }
        s += __shfl_xor(s, 16); s += __shfl_xor(s, 32);
        q += __shfl_xor(q, 16); q += __shfl_xor(q, 32);
        if (hi == 0) { sred[0][wave][col] = s; sred[1][wave][col] = q; }
    }
    __syncthreads();
    for (int t = threadIdx.x; t < N; t += 256) {
        float s = sred[0][0][t] + sred[0][1][t] + sred[0][2][t] + sred[0][3][t];
        float q = sred[1][0][t] + sred[1][1][t] + sred[1][2][t] + sred[1][3][t];
        atomicAdd(&ssum[t], s); atomicAdd(&ssq[t], q);
    }
}

// ===== k_edge6b: CSR node-parallel, low-VGPR (proven round 15 A/B winner) =====
// acc split in halves, hv via LDS; single-wave block so LDS ops are program-ordered.
__global__ __launch_bounds__(64, 8) void k_edge6b(const bf16* __restrict__ eaP,
                                                  const void* __restrict__ EA,
                                                  const int* __restrict__ eids,
                                                  const bf16* __restrict__ Wf,
                                                  const bf16* __restrict__ bias,
                                                  const int* __restrict__ srcs,
                                                  const int* __restrict__ rowptr,
                                                  const bf16* __restrict__ h,
                                                  float* __restrict__ agg,
                                                  const int* __restrict__ flags) {
    __shared__ short sm[16 * 132];
    __shared__ unsigned hbuf[16 * 64];
    bool f32 = (flags[0] == 0);
    int lane = threadIdx.x & 63;
    int d = blockIdx.x;
    int start = rowptr[d], end = rowptr[d + 1];
    int koff = (lane >> 4) << 3;
    int l2 = lane * 2;
    int hi = lane >> 4, coll = lane & 15;
    int rbase = hi * 4;
    float bx = b2f(bias[l2]), by = b2f(bias[l2 + 1]);
    float rx = 0.f, ry = 0.f;
    bool first = true;
    for (int c = start; c < end; c += 16) {
        int eidx = c + (lane & 15);
        int ok_l = (eidx < end) ? 1 : 0;
        int sc_l = ok_l ? srcs[eidx] : 0;
        bf16x8 a0, a1;
        if (eaP) {
            const bf16* ap = eaP + (size_t)eidx * 64 + koff;
            a0 = ok_l ? ld_frag(ap)      : zero8();
            a1 = ok_l ? ld_frag(ap + 32) : zero8();
        } else {
            size_t abase = ok_l ? ((size_t)eids[eidx] * 64 + koff) : 0;
            a0 = ok_l ? ld_a8(EA, abase, f32)      : zero8();
            a1 = ok_l ? ld_a8(EA, abase + 32, f32) : zero8();
        }
        if (!first) __syncthreads();
        first = false;
        // half 0: fragments 0..3 -> sm cols 0..63
        {
            f32x4 acc[4] = {};
#pragma unroll
            for (int j = 0; j < 4; ++j) {
                acc[j] = __builtin_amdgcn_mfma_f32_16x16x32_bf16(
                    a0, ld_frag(Wf + (((0 * 8 + j) * 64 + lane) << 3)), acc[j], 0, 0, 0);
                acc[j] = __builtin_amdgcn_mfma_f32_16x16x32_bf16(
                    a1, ld_frag(Wf + (((1 * 8 + j) * 64 + lane) << 3)), acc[j], 0, 0, 0);
            }
#pragma unroll
            for (int j = 0; j < 4; ++j)
#pragma unroll
                for (int r = 0; r < 4; ++r)
                    sm[(rbase + r) * 132 + j * 16 + coll] = f2bs(acc[j][r]);
        }
        // half 1: fragments 4..7 -> sm cols 64..127
        {
            f32x4 acc[4] = {};
#pragma unroll
            for (int j = 0; j < 4; ++j) {
                acc[j] = __builtin_amdgcn_mfma_f32_16x16x32_bf16(
                    a0, ld_frag(Wf + (((0 * 8 + 4 + j) * 64 + lane) << 3)), acc[j], 0, 0, 0);
                acc[j] = __builtin_amdgcn_mfma_f32_16x16x32_bf16(
                    a1, ld_frag(Wf + (((1 * 8 + 4 + j) * 64 + lane) << 3)), acc[j], 0, 0, 0);
            }
#pragma unroll
            for (int j = 0; j < 4; ++j)
#pragma unroll
                for (int r = 0; r < 4; ++r)
                    sm[(rbase + r) * 132 + (4 + j) * 16 + coll] = f2bs(acc[j][r]);
        }
        // h prefetch through LDS (no 16-register residency)
#pragma unroll
        for (int e = 0; e < 16; ++e) {
            int s = __shfl(sc_l, e);
            hbuf[e * 64 + lane] = *reinterpret_cast<const unsigned*>(
                reinterpret_cast<const unsigned short*>(h) + (size_t)s * 128 + l2);
        }
        __syncthreads();
        int lim = end - c; if (lim > 16) lim = 16;
        for (int e = 0; e < lim; ++e) {
            unsigned mu = *reinterpret_cast<const unsigned*>(&sm[e * 132 + l2]);
            unsigned hu = hbuf[e * 64 + lane];
            float vx = u2f_lo(mu) + u2f_lo(hu) + bx;
            float vy = u2f_hi(mu) + u2f_hi(hu) + by;
            rx += fmaxf(vx, 0.f); ry += fmaxf(vy, 0.f);
        }
    }
    agg[(size_t)d * 128 + l2]     = rx;
    agg[(size_t)d * 128 + l2 + 1] = ry;
}

// ---------- legacy unsorted edge kernel (tier C fallback)
__global__ __launch_bounds__(256) void k_edge(const void* __restrict__ EA,
                                              const bf16* __restrict__ Wf,
                                              const bf16* __restrict__ bias,
                                              const void* __restrict__ ei,
                                              const bf16* __restrict__ h,
                                              float* __restrict__ agg,
                                              const int* __restrict__ flags) {
    bool f32 = (flags[0] == 0);
    bool i64 = (flags[1] == 1);
    const int K = 64, NF = 8;
    int lane = threadIdx.x & 63, wave = threadIdx.x >> 6;
    int rowbase = blockIdx.x * 64 + wave * 16;
    int colbase = blockIdx.y * 64;
    int arow = rowbase + (lane & 15);
    size_t abase = (size_t)arow * K + ((lane >> 4) << 3);
    f32x4 acc[4] = {};
#pragma unroll
    for (int ks = 0; ks < 2; ++ks) {
        bf16x8 a = ld_a8(EA, abase + ks * 32, f32);
#pragma unroll
        for (int f = 0; f < 4; ++f) {
            bf16x8 b = ld_frag(Wf + (((ks * NF + colbase / 16 + f) * 64 + lane) << 3));
            acc[f] = __builtin_amdgcn_mfma_f32_16x16x32_bf16(a, b, acc[f], 0, 0, 0);
        }
    }
    int erow = rowbase + ((lane >> 4) << 2);
    int coll = lane & 15;
    float bv[4];
#pragma unroll
    for (int f = 0; f < 4; ++f) bv[f] = b2f(bias[colbase + f * 16 + coll]);
#pragma unroll
    for (int r = 0; r < 4; ++r) {
        int e = erow + r;
        int s, d;
        if (i64) {
            s = (int)((const long long*)ei)[e];
            d = (int)((const long long*)ei)[NEDGES + e];
        } else {
            s = ((const int*)ei)[e];
            d = ((const int*)ei)[NEDGES + e];
        }
        if ((unsigned)s >= NNODES || (unsigned)d >= NNODES) continue;
        const bf16* hp = h + (size_t)s * HIDDEN;
        float* gp = agg + (size_t)d * HIDDEN;
#pragma unroll
        for (int f = 0; f < 4; ++f) {
            int col = colbase + f * 16 + coll;
            float v = acc[f][r] + bv[f] + b2f(hp[col]);
            if (v > 0.f) atomicAdd(gp + col, v);
        }
    }
}

// ---------- fused BN-finalize + normalize + exact GELU (x4) + optional agg-zero tail
template<int N>
__global__ void k_bngelu4(const bf16* __restrict__ y, const float* __restrict__ ssum,
                          const float* __restrict__ ssq, const bf16* __restrict__ g,
                          const bf16* __restrict__ beta, bf16* __restrict__ z,
                          void* __restrict__ out_base, int slice,
                          const int* __restrict__ flags,
                          float* __restrict__ aggz, int aggn4) {
    __shared__ float sscale[N], sshift[N];
    for (int c = threadIdx.x; c < N; c += 256) {
        const float invM = 1.f / (float)NNODES;
        float mean = ssum[c] * invM;
        float var  = ssq[c] * invM - mean * mean;
        float a = b2f(g[c]) * rsqrtf(fmaxf(var, 0.f) + 1e-5f);
        sscale[c] = a;
        sshift[c] = b2f(beta[c]) - mean * a;
    }
    __syncthreads();
    bool outb = (flags[0] == 1);
    const int total4 = NNODES * N / 4;
    for (int i4 = blockIdx.x * 256 + threadIdx.x; i4 < total4; i4 += gridDim.x * 256) {
        int i = i4 * 4;
        int col = i & (N - 1);
        ushort4 yv = ((const ushort4*)y)[i4];
        float g0 = gelu_ex(u2f_lo(yv.x) * sscale[col]     + sshift[col]);
        float g1 = gelu_ex(u2f_lo(yv.y) * sscale[col + 1] + sshift[col + 1]);
        float g2 = gelu_ex(u2f_lo(yv.z) * sscale[col + 2] + sshift[col + 2]);
        float g3 = gelu_ex(u2f_lo(yv.w) * sscale[col + 3] + sshift[col + 3]);
        ushort4 zv;
        zv.x = (unsigned short)f2bs(g0); zv.y = (unsigned short)f2bs(g1);
        zv.z = (unsigned short)f2bs(g2); zv.w = (unsigned short)f2bs(g3);
        ((ushort4*)z)[i4] = zv;
        if (slice >= 0) {
            int row = i / N;
            size_t ob = (size_t)row * 512 + (size_t)slice * 128 + col;
            if (outb) {
                *reinterpret_cast<ushort4*>((unsigned short*)out_base + ob) = zv;
            } else {
                float4 gv = {g0, g1, g2, g3};
                *reinterpret_cast<float4*>((float*)out_base + ob) = gv;
            }
        }
    }
    if (aggz) {
        float4 zzz = {0.f, 0.f, 0.f, 0.f};
        for (int i4 = blockIdx.x * 256 + threadIdx.x; i4 < aggn4; i4 += gridDim.x * 256)
            ((float4*)aggz)[i4] = zzz;
    }
}

extern "C" void kernel_launch(void* const* d_in, const int* in_sizes, int n_in,
                              void* d_out, int out_size, void* d_ws, size_t ws_size,
                              hipStream_t stream) {
    const void* x      = d_in[0];
    const void* ei     = d_in[1];
    const void* ea     = d_in[2];
    const void* emb_w  = d_in[3];
    const void* emb_b  = d_in[4];
    const void* emb_g  = d_in[5];
    const void* emb_bt = d_in[6];
    const void* eps    = d_in[7];
    const void* lin_w  = d_in[8];
    const void* lin_b  = d_in[9];
    const void* w1     = d_in[10];
    const void* b1     = d_in[11];
    const void* g1     = d_in[12];
    const void* bt1    = d_in[13];
    const void* w2     = d_in[14];
    const void* b2     = d_in[15];
    const void* g2     = d_in[16];
    const void* bt2    = d_in[17];

    char* ws = (char*)d_ws;
    int*   flags  = (int*)ws;
    float* stats  = (float*)(ws + 1024);
    bf16*  canon  = (bf16*)(ws + 16384);
    bf16*  wf0    = (bf16*)(ws + 32768);
    bf16*  lin_wf = wf0 + 16384;
    bf16*  w1f    = wf0 + 40960;
    bf16*  w2f    = wf0 + 139264;
    bf16*  bufH   = (bf16*)(ws + 524288);       // [50000,128] bf16 (y0 / h)
    bf16*  bufA   = (bf16*)(ws + 13324288);     // [50000,128] bf16 (y2)
    char*  bufC   = (ws + 26124288);            // 25.6 MB (agg fp32 | y1 bf16)
    float* aggf   = (float*)bufC;
    bf16*  y1     = (bf16*)bufC;
    const size_t SB = 51724288;
    int*  rowptr  = (int*)(ws + SB);
    int*  cursorA = (int*)(ws + SB + 200704);
    int*  srcs    = (int*)(ws + SB + 401408);
    int*  dsts    = (int*)(ws + SB + 3601408);
    int*  eids    = (int*)(ws + SB + 6801408);
    bf16* eaP     = (bf16*)(ws + SB + 10001408);
    int*  cursorB = (int*)bufA;                       // dead region during sort phase
    int*  pos_of  = (int*)(ws + 13324288 + 1048576);  // bufA+1MB, dead during sort phase
    const unsigned long long TIERA_NEED = SB + 10001408ull + 102400000ull;
    const unsigned long long TIERB_NEED = SB + 10001408ull;
    bool tierA = ws_size >= TIERA_NEED;
    bool tierB = !tierA && ws_size >= TIERB_NEED;
    bool sorted = tierA || tierB;
    const int AGGN4 = NNODES * HIDDEN / 4;

    k_init<<<256, 256, 0, stream>>>(stats, cursorA, cursorB, sorted ? 1 : 0);
    k_detect_cvt<<<1, 256, 0, stream>>>((const unsigned*)emb_g, (const unsigned*)ei, flags,
                                        emb_b, emb_g, emb_bt, eps, lin_b, b1, g1, bt1,
                                        b2, g2, bt2, canon);
    k_repack_all<<<928, 256, 0, stream>>>(emb_w, lin_w, w1, w2, wf0, flags);

    if (sorted) {
        k_hist<<<1024, 256, 0, stream>>>(ei, cursorA, flags);
        k_scan<<<1, 1024, 0, stream>>>(cursorA, rowptr);
        k_scatter<<<1024, 256, 0, stream>>>(ei, rowptr, cursorB, srcs, dsts, eids,
                                            pos_of, flags);
        if (tierA) k_permEA3<<<6250, 256, 0, stream>>>(ea, pos_of, eaP, flags);
    }

    // ---- node embed (stats slot 0); tier-C needs agg pre-zeroed via bngelu tail
    float* aggz0 = sorted ? (float*)nullptr : aggf;
    k_gemm<128, 8><<<782, 256, 0, stream>>>(x, wf0, canon + C_EMB_B, bufH, NNODES,
                                            stats, stats + 256, flags, 1);
    k_bngelu4<128><<<2048, 256, 0, stream>>>(bufH, stats, stats + 256,
                                             canon + C_EMB_G, canon + C_EMB_BT,
                                             bufH, d_out, 0, flags, aggz0, AGGN4);

    for (int i = 0; i < 3; ++i) {
        float* s1 = stats + (size_t)(1 + 2 * i) * 512;
        float* s2 = stats + (size_t)(2 + 2 * i) * 512;
        if (sorted) {
            const bf16* pA = tierA ? eaP : (const bf16*)nullptr;
            const void* pE = tierA ? (const void*)nullptr : ea;
            const int*  pI = tierA ? (const int*)nullptr : eids;
            k_edge6b<<<NNODES, 64, 0, stream>>>(pA, pE, pI,
                                                lin_wf + i * 8192,
                                                canon + C_LIN_B + i * 128,
                                                srcs, rowptr, bufH, aggf, flags);
        } else {
            k_edge<<<dim3(12500, 2), 256, 0, stream>>>(ea, lin_wf + i * 8192,
                                                       canon + C_LIN_B + i * 128, ei,
                                                       bufH, aggf, flags);
        }
        // MLP layer 1 with fused zin (stats slot 1+2i); y1 = raw pre-BN output
        k_gemm_zin<16><<<782, 256, 0, stream>>>(bufH, aggf, canon + C_EPS, i,
                                                w1f + i * 32768, canon + C_B1 + i * 256,
                                                y1, NNODES, s1, s1 + 256);
        // MLP layer 2 with consumer-fused BN+GELU on y1 (stats slot 2+2i)
        k_gemm_bn<8><<<782, 256, 0, stream>>>(y1, s1, s1 + 256, canon + C_G1 + i * 256,
                                              canon + C_BT1 + i * 256,
                                              w2f + i * 32768, canon + C_B2 + i * 128,
                                              bufA, NNODES, s2, s2 + 256);
        // slice bngelu; tier-C zero-tail for next layer's atomics (sorted path: none)
        float* aggz = (!sorted && i < 2) ? aggf : (float*)nullptr;
        k_bngelu4<128><<<2048, 256, 0, stream>>>(bufA, s2, s2 + 256, canon + C_G2 + i * 128,
                                                 canon + C_BT2 + i * 128, bufH, d_out,
                                                 i + 1, flags, aggz, AGGN4);
    }
}

// Round 17
// 828.607 us; speedup vs baseline: 1.2162x; 1.0031x over previous
//
#include <hip/hip_runtime.h>
#include <hip/hip_bf16.h>

typedef __hip_bfloat16 bf16;
typedef __attribute__((ext_vector_type(8))) short bf16x8;
typedef __attribute__((ext_vector_type(4))) float f32x4;

#define HIDDEN 128
#define NNODES 50000
#define NEDGES 800000

static __device__ __forceinline__ float b2f(bf16 v) { return __bfloat162float(v); }
static __device__ __forceinline__ short f2bs(float f) {
    bf16 b = __float2bfloat16(f);
    return *reinterpret_cast<const short*>(&b);
}
static __device__ __forceinline__ float bs2f(short s) {
    unsigned x = ((unsigned)(unsigned short)s) << 16;
    return *reinterpret_cast<const float*>(&x);
}
static __device__ __forceinline__ bf16x8 ld_frag(const bf16* p) {
    return *reinterpret_cast<const bf16x8*>(p);
}
static __device__ __forceinline__ bf16x8 zero8() {
    bf16x8 z = {0, 0, 0, 0, 0, 0, 0, 0};
    return z;
}
static __device__ __forceinline__ float u2f_lo(unsigned u) {
    unsigned x = u << 16; return *reinterpret_cast<const float*>(&x);
}
static __device__ __forceinline__ float u2f_hi(unsigned u) {
    unsigned x = u & 0xffff0000u; return *reinterpret_cast<const float*>(&x);
}
static __device__ __forceinline__ bf16x8 ld_a8(const void* base, size_t off, bool f32) {
    if (!f32) return *reinterpret_cast<const bf16x8*>((const bf16*)base + off);
    const float4* p = reinterpret_cast<const float4*>((const float*)base + off);
    float4 u = p[0], w = p[1];
    bf16x8 r;
    r[0]=f2bs(u.x); r[1]=f2bs(u.y); r[2]=f2bs(u.z); r[3]=f2bs(u.w);
    r[4]=f2bs(w.x); r[5]=f2bs(w.y); r[6]=f2bs(w.z); r[7]=f2bs(w.w);
    return r;
}
static __device__ __forceinline__ float gelu_ex(float v) {
    return 0.5f * v * (1.f + erff(v * 0.70710678118654752f));
}

#define C_EMB_B   0
#define C_EMB_G   128
#define C_EMB_BT  256
#define C_EPS     384
#define C_LIN_B   400
#define C_B1      800
#define C_G1      1568
#define C_BT1     2336
#define C_B2      3104
#define C_G2      3488
#define C_BT2     3872

__global__ void k_init(float* __restrict__ stats, int* __restrict__ cursorA,
                       int* __restrict__ cursorB, int doSort) {
    int tid = blockIdx.x * 256 + threadIdx.x;
    int stride = gridDim.x * 256;
    for (int i = tid; i < 3584; i += stride) stats[i] = 0.f;
    if (doSort) for (int i = tid; i < NNODES; i += stride) cursorA[i] = 0;
    for (int i = tid; i < NNODES; i += stride) cursorB[i] = 0;
}

__global__ void k_detect_cvt(const unsigned* __restrict__ gones,
                             const unsigned* __restrict__ eiw, int* __restrict__ flags,
                             const void* emb_b, const void* emb_g, const void* emb_bt,
                             const void* eps, const void* lin_b, const void* b1,
                             const void* g1, const void* bt1, const void* b2,
                             const void* g2, const void* bt2, bf16* __restrict__ canon) {
    __shared__ int sf;
    if (threadIdx.x == 0) {
        int f0 = (gones[0] == 0x3F803F80u) ? 1 : 0;
        unsigned s = 0;
        for (int i = 1; i < 64; i += 2) s |= eiw[i];
        flags[0] = f0; flags[1] = (s == 0u) ? 1 : 0;
        sf = f0;
    }
    __syncthreads();
    bool f32 = (sf == 0);
    const void* ps[11] = {emb_b, emb_g, emb_bt, eps, lin_b, b1, g1, bt1, b2, g2, bt2};
    const int   ns[11] = {128, 128, 128, 3, 384, 768, 768, 768, 384, 384, 384};
    const int   os[11] = {C_EMB_B, C_EMB_G, C_EMB_BT, C_EPS, C_LIN_B, C_B1,
                          C_G1, C_BT1, C_B2, C_G2, C_BT2};
    for (int seg = 0; seg < 11; ++seg)
        for (int i = threadIdx.x; i < ns[seg]; i += 256) {
            short v = f32 ? f2bs(((const float*)ps[seg])[i]) : ((const short*)ps[seg])[i];
            ((short*)canon)[os[seg] + i] = v;
        }
}

__global__ void k_repack_all(const void* __restrict__ emb_w, const void* __restrict__ lin_w,
                             const void* __restrict__ w1, const void* __restrict__ w2,
                             bf16* __restrict__ Wf, const int* __restrict__ flags) {
    const int starts[11] = {0, 16384, 24576, 32768, 40960, 73728, 106496,
                            139264, 172032, 204800, 237568};
    int idx = blockIdx.x * 256 + threadIdx.x;
    if (idx >= 237568) return;
    bool f32 = (flags[0] == 0);
    int seg = 0;
    while (idx >= starts[seg + 1]) ++seg;
    int local = idx - starts[seg];
    const void* base; long long eoff; int K, N;
    if (seg == 0)      { base = emb_w; eoff = 0;                          K = 128; N = 128; }
    else if (seg <= 3) { base = lin_w; eoff = (long long)(seg - 1) * 8192;  K = 64;  N = 128; }
    else if (seg <= 6) { base = w1;    eoff = (long long)(seg - 4) * 32768; K = 128; N = 256; }
    else               { base = w2;    eoff = (long long)(seg - 7) * 32768; K = 256; N = 128; }
    int j    = local & 7;
    int lane = (local >> 3) & 63;
    int rest = local >> 9;
    int NF   = N >> 4;
    int ks   = rest / NF;
    int nf   = rest - ks * NF;
    int k = ks * 32 + ((lane >> 4) << 3) + j;
    int n = (nf << 4) + (lane & 15);
    long long src = eoff + (long long)k * N + n;
    short v = f32 ? f2bs(((const float*)base)[src]) : ((const short*)base)[src];
    ((short*)Wf)[idx] = v;
}

// ================= sort by dst (counting sort) =================
__global__ void k_hist(const void* __restrict__ ei, int* __restrict__ deg,
                       const int* __restrict__ flags) {
    bool i64 = (flags[1] == 1);
    for (int e = blockIdx.x * 256 + threadIdx.x; e < NEDGES; e += gridDim.x * 256) {
        int d = i64 ? (int)((const long long*)ei)[NEDGES + e] : ((const int*)ei)[NEDGES + e];
        if ((unsigned)d < NNODES) atomicAdd(&deg[d], 1);
    }
}

__global__ __launch_bounds__(1024) void k_scan(const int* __restrict__ deg,
                                               int* __restrict__ rowptr) {
    __shared__ int part[1024];
    const int CH = 49;
    int t = threadIdx.x;
    int lo = t * CH, hi = lo + CH; if (hi > NNODES) hi = NNODES; if (lo > NNODES) lo = NNODES;
    int s = 0;
    for (int i = lo; i < hi; ++i) s += deg[i];
    part[t] = s;
    __syncthreads();
    for (int off = 1; off < 1024; off <<= 1) {
        int v = (t >= off) ? part[t - off] : 0;
        __syncthreads();
        part[t] += v;
        __syncthreads();
    }
    int run = (t == 0) ? 0 : part[t - 1];
    for (int i = lo; i < hi; ++i) { rowptr[i] = run; run += deg[i]; }
    if (t == 1023) rowptr[NNODES] = run;
}

__global__ void k_scatter(const void* __restrict__ ei, const int* __restrict__ rowptr,
                          int* __restrict__ cursor, int* __restrict__ srcs,
                          int* __restrict__ dsts, int* __restrict__ eids,
                          int* __restrict__ pos_of,
                          const int* __restrict__ flags) {
    bool i64 = (flags[1] == 1);
    for (int e = blockIdx.x * 256 + threadIdx.x; e < NEDGES; e += gridDim.x * 256) {
        int s, d;
        if (i64) {
            s = (int)((const long long*)ei)[e];
            d = (int)((const long long*)ei)[NEDGES + e];
        } else {
            s = ((const int*)ei)[e];
            d = ((const int*)ei)[NEDGES + e];
        }
        if ((unsigned)s >= NNODES || (unsigned)d >= NNODES) { pos_of[e] = -1; continue; }
        int pos = rowptr[d] + atomicAdd(&cursor[d], 1);
        srcs[pos] = s; dsts[pos] = d; eids[pos] = e; pos_of[e] = pos;
    }
}

// ---------- permute-gather of edge_attr, LINEAR coalesced read / random row write
__global__ void k_permEA3(const void* __restrict__ EA, const int* __restrict__ pos_of,
                          bf16* __restrict__ eaP, const int* __restrict__ flags) {
    bool f32 = (flags[0] == 0);
    int tid = blockIdx.x * 256 + threadIdx.x;
    int t = tid & 7;
    int r0 = (tid >> 3) * 4;
    if (r0 >= NEDGES) return;
    int p[4];
#pragma unroll
    for (int j = 0; j < 4; ++j) p[j] = pos_of[r0 + j];
    if (f32) {
        float4 a[4], b[4];
#pragma unroll
        for (int j = 0; j < 4; ++j) {
            const float4* q = reinterpret_cast<const float4*>(
                (const float*)EA + (size_t)(r0 + j) * 64 + t * 8);
            a[j] = q[0]; b[j] = q[1];
        }
#pragma unroll
        for (int j = 0; j < 4; ++j) {
            if (p[j] < 0) continue;
            bf16x8 r;
            r[0]=f2bs(a[j].x); r[1]=f2bs(a[j].y); r[2]=f2bs(a[j].z); r[3]=f2bs(a[j].w);
            r[4]=f2bs(b[j].x); r[5]=f2bs(b[j].y); r[6]=f2bs(b[j].z); r[7]=f2bs(b[j].w);
            *reinterpret_cast<bf16x8*>(eaP + (size_t)p[j] * 64 + t * 8) = r;
        }
    } else {
        bf16x8 a[4];
#pragma unroll
        for (int j = 0; j < 4; ++j)
            a[j] = *reinterpret_cast<const bf16x8*>(
                (const bf16*)EA + (size_t)(r0 + j) * 64 + t * 8);
#pragma unroll
        for (int j = 0; j < 4; ++j) {
            if (p[j] < 0) continue;
            *reinterpret_cast<bf16x8*>(eaP + (size_t)p[j] * 64 + t * 8) = a[j];
        }
    }
}

// ================= GEMM with fused bias + BN column stats =================
template<int K, int NF>
__global__ __launch_bounds__(256) void k_gemm(const void* __restrict__ A,
                                              const bf16* __restrict__ Wf,
                                              const bf16* __restrict__ bias,
                                              bf16* __restrict__ Y, int M,
                                              float* __restrict__ ssum,
                                              float* __restrict__ ssq,
                                              const int* __restrict__ flags, int flexA) {
    const int N = NF * 16;
    __shared__ float sred[2][4][N];
    bool f32 = flexA && (flags[0] == 0);
    int lane = threadIdx.x & 63, wave = threadIdx.x >> 6;
    int rowbase = blockIdx.x * 64 + wave * 16;
    int arow = rowbase + (lane & 15);
    bool aval = (arow < M);
    size_t abase = (size_t)arow * K + ((lane >> 4) << 3);
    f32x4 acc[NF] = {};
#pragma unroll
    for (int ks = 0; ks < K / 32; ++ks) {
        bf16x8 a = aval ? ld_a8(A, abase + ks * 32, f32) : zero8();
#pragma unroll
        for (int f = 0; f < NF; ++f) {
            bf16x8 b = ld_frag(Wf + (((ks * NF + f) * 64 + lane) << 3));
            acc[f] = __builtin_amdgcn_mfma_f32_16x16x32_bf16(a, b, acc[f], 0, 0, 0);
        }
    }
    int hi = lane >> 4, coll = lane & 15;
    int crow = rowbase + hi * 4;
#pragma unroll
    for (int f = 0; f < NF; ++f) {
        int col = f * 16 + coll;
        float bv = b2f(bias[col]);
        float s = 0.f, q = 0.f;
#pragma unroll
        for (int r = 0; r < 4; ++r) {
            int row = crow + r;
            if (row < M) {
                float v = acc[f][r] + bv;
                Y[(size_t)row * N + col] = __float2bfloat16(v);
                s += v; q += v * v;
            }
        }
        s += __shfl_xor(s, 16); s += __shfl_xor(s, 32);
        q += __shfl_xor(q, 16); q += __shfl_xor(q, 32);
        if (hi == 0) { sred[0][wave][col] = s; sred[1][wave][col] = q; }
    }
    __syncthreads();
    for (int t = threadIdx.x; t < N; t += 256) {
        float s = sred[0][0][t] + sred[0][1][t] + sred[0][2][t] + sred[0][3][t];
        float q = sred[1][0][t] + sred[1][1][t] + sred[1][2][t] + sred[1][3][t];
        atomicAdd(&ssum[t], s); atomicAdd(&ssq[t], q);
    }
}

// ======= GEMM with fused zin input (A = bf16((1+eps)h + agg)), K=128 =======
template<int NF>
__global__ __launch_bounds__(256) void k_gemm_zin(const bf16* __restrict__ h,
                                                  const float* __restrict__ agg,
                                                  const bf16* __restrict__ epsc, int layer,
                                                  const bf16* __restrict__ Wf,
                                                  const bf16* __restrict__ bias,
                                                  bf16* __restrict__ Y, int M,
                                                  float* __restrict__ ssum,
                                                  float* __restrict__ ssq) {
    const int K = 128, N = NF * 16;
    __shared__ float sred[2][4][N];
    float e1 = 1.f + b2f(epsc[layer]);
    int lane = threadIdx.x & 63, wave = threadIdx.x >> 6;
    int rowbase = blockIdx.x * 64 + wave * 16;
    int arow = rowbase + (lane & 15);
    bool aval = (arow < M);
    size_t abase = (size_t)arow * K + ((lane >> 4) << 3);
    f32x4 acc[NF] = {};
#pragma unroll
    for (int ks = 0; ks < 4; ++ks) {
        bf16x8 a;
        if (aval) {
            size_t off = abase + ks * 32;
            bf16x8 hv = ld_frag(h + off);
            float4 a0 = *reinterpret_cast<const float4*>(agg + off);
            float4 a1 = *reinterpret_cast<const float4*>(agg + off + 4);
            a[0] = f2bs(e1 * bs2f(hv[0]) + a0.x);
            a[1] = f2bs(e1 * bs2f(hv[1]) + a0.y);
            a[2] = f2bs(e1 * bs2f(hv[2]) + a0.z);
            a[3] = f2bs(e1 * bs2f(hv[3]) + a0.w);
            a[4] = f2bs(e1 * bs2f(hv[4]) + a1.x);
            a[5] = f2bs(e1 * bs2f(hv[5]) + a1.y);
            a[6] = f2bs(e1 * bs2f(hv[6]) + a1.z);
            a[7] = f2bs(e1 * bs2f(hv[7]) + a1.w);
        } else {
            a = zero8();
        }
#pragma unroll
        for (int f = 0; f < NF; ++f) {
            bf16x8 b = ld_frag(Wf + (((ks * NF + f) * 64 + lane) << 3));
            acc[f] = __builtin_amdgcn_mfma_f32_16x16x32_bf16(a, b, acc[f], 0, 0, 0);
        }
    }
    int hi = lane >> 4, coll = lane & 15;
    int crow = rowbase + hi * 4;
#pragma unroll
    for (int f = 0; f < NF; ++f) {
        int col = f * 16 + coll;
        float bv = b2f(bias[col]);
        float s = 0.f, q = 0.f;
#pragma unroll
        for (int r = 0; r < 4; ++r) {
            int row = crow + r;
            if (row < M) {
                float v = acc[f][r] + bv;
                Y[(size_t)row * N + col] = __float2bfloat16(v);
                s += v; q += v * v;
            }
        }
        s += __shfl_xor(s, 16); s += __shfl_xor(s, 32);
        q += __shfl_xor(q, 16); q += __shfl_xor(q, 32);
        if (hi == 0) { sred[0][wave][col] = s; sred[1][wave][col] = q; }
    }
    __syncthreads();
    for (int t = threadIdx.x; t < N; t += 256) {
        float s = sred[0][0][t] + sred[0][1][t] + sred[0][2][t] + sred[0][3][t];
        float q = sred[1][0][t] + sred[1][1][t] + sred[1][2][t] + sred[1][3][t];
        atomicAdd(&ssum[t], s); atomicAdd(&ssq[t], q);
    }
}

// ======= GEMM with fused BN+GELU on A (A = gelu(bn(y1raw))), K=256 =======
template<int NF>
__global__ __launch_bounds__(256) void k_gemm_bn(const bf16* __restrict__ A,
                                                 const float* __restrict__ ssumIn,
                                                 const float* __restrict__ ssqIn,
                                                 const bf16* __restrict__ gIn,
                                                 const bf16* __restrict__ btIn,
                                                 const bf16* __restrict__ Wf,
                                                 const bf16* __restrict__ bias,
                                                 bf16* __restrict__ Y, int M,
                                                 float* __restrict__ ssum,
                                                 float* __restrict__ ssq) {
    const int K = 256, N = NF * 16;
    __shared__ float sscale[K], sshift[K];
    __shared__ float sred[2][4][N];
    for (int c = threadIdx.x; c < K; c += 256) {
        const float invM = 1.f / (float)NNODES;
        float mean = ssumIn[c] * invM;
        float var  = ssqIn[c] * invM - mean * mean;
        float a = b2f(gIn[c]) * rsqrtf(fmaxf(var, 0.f) + 1e-5f);
        sscale[c] = a;
        sshift[c] = b2f(btIn[c]) - mean * a;
    }
    __syncthreads();
    int lane = threadIdx.x & 63, wave = threadIdx.x >> 6;
    int rowbase = blockIdx.x * 64 + wave * 16;
    int arow = rowbase + (lane & 15);
    bool aval = (arow < M);
    int koff = (lane >> 4) << 3;
    size_t abase = (size_t)arow * K + koff;
    f32x4 acc[NF] = {};
#pragma unroll
    for (int ks = 0; ks < 8; ++ks) {
        bf16x8 a;
        if (aval) {
            bf16x8 raw = ld_frag(A + abase + ks * 32);
            int c0 = ks * 32 + koff;
#pragma unroll
            for (int j = 0; j < 8; ++j) {
                float v = bs2f(raw[j]) * sscale[c0 + j] + sshift[c0 + j];
                a[j] = f2bs(gelu_ex(v));
            }
        } else {
            a = zero8();
        }
#pragma unroll
        for (int f = 0; f < NF; ++f) {
            bf16x8 b = ld_frag(Wf + (((ks * NF + f) * 64 + lane) << 3));
            acc[f] = __builtin_amdgcn_mfma_f32_16x16x32_bf16(a, b, acc[f], 0, 0, 0);
        }
    }
    int hi = lane >> 4, coll = lane & 15;
    int crow = rowbase + hi * 4;
#pragma unroll
    for (int f = 0; f < NF; ++f) {
        int col = f * 16 + coll;
        float bv = b2f(bias[col]);
        float s = 0.f, q = 0.f;
#pragma unroll
        for (int r = 0; r < 4; ++r) {
            int row = crow + r;
            if (row < M) {
                float v = acc[f][r] + bv;
                Y[(size_t)row * N + col] = __float2bfloat16(v);
                s += v; q += v * v;
            }
        }
        s += __shfl_xor(s, 16); s += __shfl_xor(s, 32);
        q += __shfl_xor(q, 16); q += __shfl_xor(q, 32);
        if (hi == 0) { sred[0][wave][col] = s; sred[1][wave][col] = q; }
    }
    __syncthreads();
    for (int t = threadIdx.x; t < N; t += 256) {
        float s = sred[0][0][t] + sred[0][1][t] + sred[0][2][t] + sred[0][3][t];
        float q = sred[1][0][t] + sred[1][1][t] + sred[1][2][t] + sred[1][3][t];
        atomicAdd(&ssum[t], s); atomicAdd(&ssq[t], q);
    }
}

// ===== k_edge6b: CSR node-parallel, low-VGPR (proven; layers 0/2) =====
__global__ __launch_bounds__(64, 8) void k_edge6b(const bf16* __restrict__ eaP,
                                                  const void* __restrict__ EA,
                                                  const int* __restrict__ eids,
                                                  const bf16* __restrict__ Wf,
                                                  const bf16* __restrict__ bias,
                                                  const int* __restrict__ srcs,
                                                  const int* __restrict__ rowptr,
                                                  const bf16* __restrict__ h,
                                                  float* __restrict__ agg,
                                                  const int* __restrict__ flags) {
    __shared__ short sm[16 * 132];
    __shared__ unsigned hbuf[16 * 64];
    bool f32 = (flags[0] == 0);
    int lane = threadIdx.x & 63;
    int d = blockIdx.x;
    int start = rowptr[d], end = rowptr[d + 1];
    int koff = (lane >> 4) << 3;
    int l2 = lane * 2;
    int hi = lane >> 4, coll = lane & 15;
    int rbase = hi * 4;
    float bx = b2f(bias[l2]), by = b2f(bias[l2 + 1]);
    float rx = 0.f, ry = 0.f;
    bool first = true;
    for (int c = start; c < end; c += 16) {
        int eidx = c + (lane & 15);
        int ok_l = (eidx < end) ? 1 : 0;
        int sc_l = ok_l ? srcs[eidx] : 0;
        bf16x8 a0, a1;
        if (eaP) {
            const bf16* ap = eaP + (size_t)eidx * 64 + koff;
            a0 = ok_l ? ld_frag(ap)      : zero8();
            a1 = ok_l ? ld_frag(ap + 32) : zero8();
        } else {
            size_t abase = ok_l ? ((size_t)eids[eidx] * 64 + koff) : 0;
            a0 = ok_l ? ld_a8(EA, abase, f32)      : zero8();
            a1 = ok_l ? ld_a8(EA, abase + 32, f32) : zero8();
        }
        if (!first) __syncthreads();
        first = false;
        {
            f32x4 acc[4] = {};
#pragma unroll
            for (int j = 0; j < 4; ++j) {
                acc[j] = __builtin_amdgcn_mfma_f32_16x16x32_bf16(
                    a0, ld_frag(Wf + (((0 * 8 + j) * 64 + lane) << 3)), acc[j], 0, 0, 0);
                acc[j] = __builtin_amdgcn_mfma_f32_16x16x32_bf16(
                    a1, ld_frag(Wf + (((1 * 8 + j) * 64 + lane) << 3)), acc[j], 0, 0, 0);
            }
#pragma unroll
            for (int j = 0; j < 4; ++j)
#pragma unroll
                for (int r = 0; r < 4; ++r)
                    sm[(rbase + r) * 132 + j * 16 + coll] = f2bs(acc[j][r]);
        }
        {
            f32x4 acc[4] = {};
#pragma unroll
            for (int j = 0; j < 4; ++j) {
                acc[j] = __builtin_amdgcn_mfma_f32_16x16x32_bf16(
                    a0, ld_frag(Wf + (((0 * 8 + 4 + j) * 64 + lane) << 3)), acc[j], 0, 0, 0);
                acc[j] = __builtin_amdgcn_mfma_f32_16x16x32_bf16(
                    a1, ld_frag(Wf + (((1 * 8 + 4 + j) * 64 + lane) << 3)), acc[j], 0, 0, 0);
            }
#pragma unroll
            for (int j = 0; j < 4; ++j)
#pragma unroll
                for (int r = 0; r < 4; ++r)
                    sm[(rbase + r) * 132 + (4 + j) * 16 + coll] = f2bs(acc[j][r]);
        }
#pragma unroll
        for (int e = 0; e < 16; ++e) {
            int s = __shfl(sc_l, e);
            hbuf[e * 64 + lane] = *reinterpret_cast<const unsigned*>(
                reinterpret_cast<const unsigned short*>(h) + (size_t)s * 128 + l2);
        }
        __syncthreads();
        int lim = end - c; if (lim > 16) lim = 16;
        for (int e = 0; e < lim; ++e) {
            unsigned mu = *reinterpret_cast<const unsigned*>(&sm[e * 132 + l2]);
            unsigned hu = hbuf[e * 64 + lane];
            float vx = u2f_lo(mu) + u2f_lo(hu) + bx;
            float vy = u2f_hi(mu) + u2f_hi(hu) + by;
            rx += fmaxf(vx, 0.f); ry += fmaxf(vy, 0.f);
        }
    }
    agg[(size_t)d * 128 + l2]     = rx;
    agg[(size_t)d * 128 + l2 + 1] = ry;
}

// ===== k_edge6c: 6b + next-chunk register prefetch (A/B on layer 1) =====
// Register-only change: next chunk's srcs + A-fragments issued before the reduce;
// LDS structure and all write->read orderings identical to proven 6b.
__global__ __launch_bounds__(64, 8) void k_edge6c(const bf16* __restrict__ eaP,
                                                  const void* __restrict__ EA,
                                                  const int* __restrict__ eids,
                                                  const bf16* __restrict__ Wf,
                                                  const bf16* __restrict__ bias,
                                                  const int* __restrict__ srcs,
                                                  const int* __restrict__ rowptr,
                                                  const bf16* __restrict__ h,
                                                  float* __restrict__ agg,
                                                  const int* __restrict__ flags) {
    __shared__ short sm[16 * 132];
    __shared__ unsigned hbuf[16 * 64];
    bool f32 = (flags[0] == 0);
    int lane = threadIdx.x & 63;
    int d = blockIdx.x;
    int start = rowptr[d], end = rowptr[d + 1];
    int koff = (lane >> 4) << 3;
    int l2 = lane * 2;
    int hi = lane >> 4, coll = lane & 15;
    int rbase = hi * 4;
    float bx = b2f(bias[l2]), by = b2f(bias[l2 + 1]);
    float rx = 0.f, ry = 0.f;
    // prologue: load chunk 0 operands
    int ok_l = 0, sc_l = 0;
    bf16x8 a0 = zero8(), a1 = zero8();
    if (start < end) {
        int eidx = start + (lane & 15);
        ok_l = (eidx < end) ? 1 : 0;
        sc_l = ok_l ? srcs[eidx] : 0;
        if (eaP) {
            const bf16* ap = eaP + (size_t)eidx * 64 + koff;
            if (ok_l) { a0 = ld_frag(ap); a1 = ld_frag(ap + 32); }
        } else {
            size_t abase = ok_l ? ((size_t)eids[eidx] * 64 + koff) : 0;
            if (ok_l) { a0 = ld_a8(EA, abase, f32); a1 = ld_a8(EA, abase + 32, f32); }
        }
    }
    bool first = true;
    for (int c = start; c < end; c += 16) {
        if (!first) __syncthreads();
        first = false;
        {
            f32x4 acc[4] = {};
#pragma unroll
            for (int j = 0; j < 4; ++j) {
                acc[j] = __builtin_amdgcn_mfma_f32_16x16x32_bf16(
                    a0, ld_frag(Wf + (((0 * 8 + j) * 64 + lane) << 3)), acc[j], 0, 0, 0);
                acc[j] = __builtin_amdgcn_mfma_f32_16x16x32_bf16(
                    a1, ld_frag(Wf + (((1 * 8 + j) * 64 + lane) << 3)), acc[j], 0, 0, 0);
            }
#pragma unroll
            for (int j = 0; j < 4; ++j)
#pragma unroll
                for (int r = 0; r < 4; ++r)
                    sm[(rbase + r) * 132 + j * 16 + coll] = f2bs(acc[j][r]);
        }
        {
            f32x4 acc[4] = {};
#pragma unroll
            for (int j = 0; j < 4; ++j) {
                acc[j] = __builtin_amdgcn_mfma_f32_16x16x32_bf16(
                    a0, ld_frag(Wf + (((0 * 8 + 4 + j) * 64 + lane) << 3)), acc[j], 0, 0, 0);
                acc[j] = __builtin_amdgcn_mfma_f32_16x16x32_bf16(
                    a1, ld_frag(Wf + (((1 * 8 + 4 + j) * 64 + lane) << 3)), acc[j], 0, 0, 0);
            }
#pragma unroll
            for (int j = 0; j < 4; ++j)
#pragma unroll
                for (int r = 0; r < 4; ++r)
                    sm[(rbase + r) * 132 + (4 + j) * 16 + coll] = f2bs(acc[j][r]);
        }
#pragma unroll
        for (int e = 0; e < 16; ++e) {
            int s = __shfl(sc_l, e);
            hbuf[e * 64 + lane] = *reinterpret_cast<const unsigned*>(
                reinterpret_cast<const unsigned short*>(h) + (size_t)s * 128 + l2);
        }
        // ---- prefetch NEXT chunk's operands (registers only; overlaps reduce)
        int cn = c + 16;
        if (cn < end) {
            int eidx = cn + (lane & 15);
            ok_l = (eidx < end) ? 1 : 0;
            sc_l = ok_l ? srcs[eidx] : 0;
            if (eaP) {
                const bf16* ap = eaP + (size_t)eidx * 64 + koff;
                a0 = ok_l ? ld_frag(ap)      : zero8();
                a1 = ok_l ? ld_frag(ap + 32) : zero8();
            } else {
                size_t abase = ok_l ? ((size_t)eids[eidx] * 64 + koff) : 0;
                a0 = ok_l ? ld_a8(EA, abase, f32)      : zero8();
                a1 = ok_l ? ld_a8(EA, abase + 32, f32) : zero8();
            }
        }
        __syncthreads();
        int lim = end - c; if (lim > 16) lim = 16;
        for (int e = 0; e < lim; ++e) {
            unsigned mu = *reinterpret_cast<const unsigned*>(&sm[e * 132 + l2]);
            unsigned hu = hbuf[e * 64 + lane];
            float vx = u2f_lo(mu) + u2f_lo(hu) + bx;
            float vy = u2f_hi(mu) + u2f_hi(hu) + by;
            rx += fmaxf(vx, 0.f); ry += fmaxf(vy, 0.f);
        }
    }
    agg[(size_t)d * 128 + l2]     = rx;
    agg[(size_t)d * 128 + l2 + 1] = ry;
}

// ---------- legacy unsorted edge kernel (tier C fallback)
__global__ __launch_bounds__(256) void k_edge(const void* __restrict__ EA,
                                              const bf16* __restrict__ Wf,
                                              const bf16* __restrict__ bias,
                                              const void* __restrict__ ei,
                                              const bf16* __restrict__ h,
                                              float* __restrict__ agg,
                                              const int* __restrict__ flags) {
    bool f32 = (flags[0] == 0);
    bool i64 = (flags[1] == 1);
    const int K = 64, NF = 8;
    int lane = threadIdx.x & 63, wave = threadIdx.x >> 6;
    int rowbase = blockIdx.x * 64 + wave * 16;
    int colbase = blockIdx.y * 64;
    int arow = rowbase + (lane & 15);
    size_t abase = (size_t)arow * K + ((lane >> 4) << 3);
    f32x4 acc[4] = {};
#pragma unroll
    for (int ks = 0; ks < 2; ++ks) {
        bf16x8 a = ld_a8(EA, abase + ks * 32, f32);
#pragma unroll
        for (int f = 0; f < 4; ++f) {
            bf16x8 b = ld_frag(Wf + (((ks * NF + colbase / 16 + f) * 64 + lane) << 3));
            acc[f] = __builtin_amdgcn_mfma_f32_16x16x32_bf16(a, b, acc[f], 0, 0, 0);
        }
    }
    int erow = rowbase + ((lane >> 4) << 2);
    int coll = lane & 15;
    float bv[4];
#pragma unroll
    for (int f = 0; f < 4; ++f) bv[f] = b2f(bias[colbase + f * 16 + coll]);
#pragma unroll
    for (int r = 0; r < 4; ++r) {
        int e = erow + r;
        int s, d;
        if (i64) {
            s = (int)((const long long*)ei)[e];
            d = (int)((const long long*)ei)[NEDGES + e];
        } else {
            s = ((const int*)ei)[e];
            d = ((const int*)ei)[NEDGES + e];
        }
        if ((unsigned)s >= NNODES || (unsigned)d >= NNODES) continue;
        const bf16* hp = h + (size_t)s * HIDDEN;
        float* gp = agg + (size_t)d * HIDDEN;
#pragma unroll
        for (int f = 0; f < 4; ++f) {
            int col = colbase + f * 16 + coll;
            float v = acc[f][r] + bv[f] + b2f(hp[col]);
            if (v > 0.f) atomicAdd(gp + col, v);
        }
    }
}

// ---------- fused BN-finalize + normalize + exact GELU (x4) + optional agg-zero tail
template<int N>
__global__ void k_bngelu4(const bf16* __restrict__ y, const float* __restrict__ ssum,
                          const float* __restrict__ ssq, const bf16* __restrict__ g,
                          const bf16* __restrict__ beta, bf16* __restrict__ z,
                          void* __restrict__ out_base, int slice,
                          const int* __restrict__ flags,
                          float* __restrict__ aggz, int aggn4) {
    __shared__ float sscale[N], sshift[N];
    for (int c = threadIdx.x; c < N; c += 256) {
        const float invM = 1.f / (float)NNODES;
        float mean = ssum[c] * invM;
        float var  = ssq[c] * invM - mean * mean;
        float a = b2f(g[c]) * rsqrtf(fmaxf(var, 0.f) + 1e-5f);
        sscale[c] = a;
        sshift[c] = b2f(beta[c]) - mean * a;
    }
    __syncthreads();
    bool outb = (flags[0] == 1);
    const int total4 = NNODES * N / 4;
    for (int i4 = blockIdx.x * 256 + threadIdx.x; i4 < total4; i4 += gridDim.x * 256) {
        int i = i4 * 4;
        int col = i & (N - 1);
        ushort4 yv = ((const ushort4*)y)[i4];
        float g0 = gelu_ex(u2f_lo(yv.x) * sscale[col]     + sshift[col]);
        float g1 = gelu_ex(u2f_lo(yv.y) * sscale[col + 1] + sshift[col + 1]);
        float g2 = gelu_ex(u2f_lo(yv.z) * sscale[col + 2] + sshift[col + 2]);
        float g3 = gelu_ex(u2f_lo(yv.w) * sscale[col + 3] + sshift[col + 3]);
        ushort4 zv;
        zv.x = (unsigned short)f2bs(g0); zv.y = (unsigned short)f2bs(g1);
        zv.z = (unsigned short)f2bs(g2); zv.w = (unsigned short)f2bs(g3);
        ((ushort4*)z)[i4] = zv;
        if (slice >= 0) {
            int row = i / N;
            size_t ob = (size_t)row * 512 + (size_t)slice * 128 + col;
            if (outb) {
                *reinterpret_cast<ushort4*>((unsigned short*)out_base + ob) = zv;
            } else {
                float4 gv = {g0, g1, g2, g3};
                *reinterpret_cast<float4*>((float*)out_base + ob) = gv;
            }
        }
    }
    if (aggz) {
        float4 zzz = {0.f, 0.f, 0.f, 0.f};
        for (int i4 = blockIdx.x * 256 + threadIdx.x; i4 < aggn4; i4 += gridDim.x * 256)
            ((float4*)aggz)[i4] = zzz;
    }
}

extern "C" void kernel_launch(void* const* d_in, const int* in_sizes, int n_in,
                              void* d_out, int out_size, void* d_ws, size_t ws_size,
                              hipStream_t stream) {
    const void* x      = d_in[0];
    const void* ei     = d_in[1];
    const void* ea     = d_in[2];
    const void* emb_w  = d_in[3];
    const void* emb_b  = d_in[4];
    const void* emb_g  = d_in[5];
    const void* emb_bt = d_in[6];
    const void* eps    = d_in[7];
    const void* lin_w  = d_in[8];
    const void* lin_b  = d_in[9];
    const void* w1     = d_in[10];
    const void* b1     = d_in[11];
    const void* g1     = d_in[12];
    const void* bt1    = d_in[13];
    const void* w2     = d_in[14];
    const void* b2     = d_in[15];
    const void* g2     = d_in[16];
    const void* bt2    = d_in[17];

    char* ws = (char*)d_ws;
    int*   flags  = (int*)ws;
    float* stats  = (float*)(ws + 1024);
    bf16*  canon  = (bf16*)(ws + 16384);
    bf16*  wf0    = (bf16*)(ws + 32768);
    bf16*  lin_wf = wf0 + 16384;
    bf16*  w1f    = wf0 + 40960;
    bf16*  w2f    = wf0 + 139264;
    bf16*  bufH   = (bf16*)(ws + 524288);       // [50000,128] bf16 (y0 / h)
    bf16*  bufA   = (bf16*)(ws + 13324288);     // [50000,128] bf16 (y2)
    char*  bufC   = (ws + 26124288);            // 25.6 MB (agg fp32 | y1 bf16)
    float* aggf   = (float*)bufC;
    bf16*  y1     = (bf16*)bufC;
    const size_t SB = 51724288;
    int*  rowptr  = (int*)(ws + SB);
    int*  cursorA = (int*)(ws + SB + 200704);
    int*  srcs    = (int*)(ws + SB + 401408);
    int*  dsts    = (int*)(ws + SB + 3601408);
    int*  eids    = (int*)(ws + SB + 6801408);
    bf16* eaP     = (bf16*)(ws + SB + 10001408);
    int*  cursorB = (int*)bufA;                       // dead region during sort phase
    int*  pos_of  = (int*)(ws + 13324288 + 1048576);  // bufA+1MB, dead during sort phase
    const unsigned long long TIERA_NEED = SB + 10001408ull + 102400000ull;
    const unsigned long long TIERB_NEED = SB + 10001408ull;
    bool tierA = ws_size >= TIERA_NEED;
    bool tierB = !tierA && ws_size >= TIERB_NEED;
    bool sorted = tierA || tierB;
    const int AGGN4 = NNODES * HIDDEN / 4;

    k_init<<<256, 256, 0, stream>>>(stats, cursorA, cursorB, sorted ? 1 : 0);
    k_detect_cvt<<<1, 256, 0, stream>>>((const unsigned*)emb_g, (const unsigned*)ei, flags,
                                        emb_b, emb_g, emb_bt, eps, lin_b, b1, g1, bt1,
                                        b2, g2, bt2, canon);
    k_repack_all<<<928, 256, 0, stream>>>(emb_w, lin_w, w1, w2, wf0, flags);

    if (sorted) {
        k_hist<<<1024, 256, 0, stream>>>(ei, cursorA, flags);
        k_scan<<<1, 1024, 0, stream>>>(cursorA, rowptr);
        k_scatter<<<1024, 256, 0, stream>>>(ei, rowptr, cursorB, srcs, dsts, eids,
                                            pos_of, flags);
        if (tierA) k_permEA3<<<6250, 256, 0, stream>>>(ea, pos_of, eaP, flags);
    }

    // ---- node embed (stats slot 0); tier-C needs agg pre-zeroed via bngelu tail
    float* aggz0 = sorted ? (float*)nullptr : aggf;
    k_gemm<128, 8><<<782, 256, 0, stream>>>(x, wf0, canon + C_EMB_B, bufH, NNODES,
                                            stats, stats + 256, flags, 1);
    k_bngelu4<128><<<2048, 256, 0, stream>>>(bufH, stats, stats + 256,
                                             canon + C_EMB_G, canon + C_EMB_BT,
                                             bufH, d_out, 0, flags, aggz0, AGGN4);

    for (int i = 0; i < 3; ++i) {
        float* s1 = stats + (size_t)(1 + 2 * i) * 512;
        float* s2 = stats + (size_t)(2 + 2 * i) * 512;
        if (sorted) {
            const bf16* pA = tierA ? eaP : (const bf16*)nullptr;
            const void* pE = tierA ? (const void*)nullptr : ea;
            const int*  pI = tierA ? (const int*)nullptr : eids;
            if (i == 1)   // within-run A/B: prefetch variant on layer 1
                k_edge6c<<<NNODES, 64, 0, stream>>>(pA, pE, pI,
                                                    lin_wf + i * 8192,
                                                    canon + C_LIN_B + i * 128,
                                                    srcs, rowptr, bufH, aggf, flags);
            else
                k_edge6b<<<NNODES, 64, 0, stream>>>(pA, pE, pI,
                                                    lin_wf + i * 8192,
                                                    canon + C_LIN_B + i * 128,
                                                    srcs, rowptr, bufH, aggf, flags);
        } else {
            k_edge<<<dim3(12500, 2), 256, 0, stream>>>(ea, lin_wf + i * 8192,
                                                       canon + C_LIN_B + i * 128, ei,
                                                       bufH, aggf, flags);
        }
        // MLP layer 1 with fused zin (stats slot 1+2i); y1 = raw pre-BN output
        k_gemm_zin<16><<<782, 256, 0, stream>>>(bufH, aggf, canon + C_EPS, i,
                                                w1f + i * 32768, canon + C_B1 + i * 256,
                                                y1, NNODES, s1, s1 + 256);
        // MLP layer 2 with consumer-fused BN+GELU on y1 (stats slot 2+2i)
        k_gemm_bn<8><<<782, 256, 0, stream>>>(y1, s1, s1 + 256, canon + C_G1 + i * 256,
                                              canon + C_BT1 + i * 256,
                                              w2f + i * 32768, canon + C_B2 + i * 128,
                                              bufA, NNODES, s2, s2 + 256);
        // slice bngelu; tier-C zero-tail for next layer's atomics (sorted path: none)
        float* aggz = (!sorted && i < 2) ? aggf : (float*)nullptr;
        k_bngelu4<128><<<2048, 256, 0, stream>>>(bufA, s2, s2 + 256, canon + C_G2 + i * 128,
                                                 canon + C_BT2 + i * 128, bufH, d_out,
                                                 i + 1, flags, aggz, AGGN4);
    }
}

// Round 18
// 826.186 us; speedup vs baseline: 1.2197x; 1.0029x over previous
//
#include <hip/hip_runtime.h>
#include <hip/hip_bf16.h>

typedef __hip_bfloat16 bf16;
typedef __attribute__((ext_vector_type(8))) short bf16x8;
typedef __attribute__((ext_vector_type(4))) float f32x4;

#define HIDDEN 128
#define NNODES 50000
#define NEDGES 800000

static __device__ __forceinline__ float b2f(bf16 v) { return __bfloat162float(v); }
static __device__ __forceinline__ short f2bs(float f) {
    bf16 b = __float2bfloat16(f);
    return *reinterpret_cast<const short*>(&b);
}
static __device__ __forceinline__ float bs2f(short s) {
    unsigned x = ((unsigned)(unsigned short)s) << 16;
    return *reinterpret_cast<const float*>(&x);
}
static __device__ __forceinline__ bf16x8 ld_frag(const bf16* p) {
    return *reinterpret_cast<const bf16x8*>(p);
}
static __device__ __forceinline__ bf16x8 zero8() {
    bf16x8 z = {0, 0, 0, 0, 0, 0, 0, 0};
    return z;
}
static __device__ __forceinline__ float u2f_lo(unsigned u) {
    unsigned x = u << 16; return *reinterpret_cast<const float*>(&x);
}
static __device__ __forceinline__ float u2f_hi(unsigned u) {
    unsigned x = u & 0xffff0000u; return *reinterpret_cast<const float*>(&x);
}
static __device__ __forceinline__ bf16x8 ld_a8(const void* base, size_t off, bool f32) {
    if (!f32) return *reinterpret_cast<const bf16x8*>((const bf16*)base + off);
    const float4* p = reinterpret_cast<const float4*>((const float*)base + off);
    float4 u = p[0], w = p[1];
    bf16x8 r;
    r[0]=f2bs(u.x); r[1]=f2bs(u.y); r[2]=f2bs(u.z); r[3]=f2bs(u.w);
    r[4]=f2bs(w.x); r[5]=f2bs(w.y); r[6]=f2bs(w.z); r[7]=f2bs(w.w);
    return r;
}
static __device__ __forceinline__ float gelu_ex(float v) {
    return 0.5f * v * (1.f + erff(v * 0.70710678118654752f));
}

#define C_EMB_B   0
#define C_EMB_G   128
#define C_EMB_BT  256
#define C_EPS     384
#define C_LIN_B   400
#define C_B1      800
#define C_G1      1568
#define C_BT1     2336
#define C_B2      3104
#define C_G2      3488
#define C_BT2     3872

__global__ void k_init(float* __restrict__ stats, int* __restrict__ cursorA,
                       int* __restrict__ cursorB, int doSort) {
    int tid = blockIdx.x * 256 + threadIdx.x;
    int stride = gridDim.x * 256;
    for (int i = tid; i < 3584; i += stride) stats[i] = 0.f;
    if (doSort) for (int i = tid; i < NNODES; i += stride) cursorA[i] = 0;
    for (int i = tid; i < NNODES; i += stride) cursorB[i] = 0;
}

__global__ void k_detect_cvt(const unsigned* __restrict__ gones,
                             const unsigned* __restrict__ eiw, int* __restrict__ flags,
                             const void* emb_b, const void* emb_g, const void* emb_bt,
                             const void* eps, const void* lin_b, const void* b1,
                             const void* g1, const void* bt1, const void* b2,
                             const void* g2, const void* bt2, bf16* __restrict__ canon) {
    __shared__ int sf;
    if (threadIdx.x == 0) {
        int f0 = (gones[0] == 0x3F803F80u) ? 1 : 0;
        unsigned s = 0;
        for (int i = 1; i < 64; i += 2) s |= eiw[i];
        flags[0] = f0; flags[1] = (s == 0u) ? 1 : 0;
        sf = f0;
    }
    __syncthreads();
    bool f32 = (sf == 0);
    const void* ps[11] = {emb_b, emb_g, emb_bt, eps, lin_b, b1, g1, bt1, b2, g2, bt2};
    const int   ns[11] = {128, 128, 128, 3, 384, 768, 768, 768, 384, 384, 384};
    const int   os[11] = {C_EMB_B, C_EMB_G, C_EMB_BT, C_EPS, C_LIN_B, C_B1,
                          C_G1, C_BT1, C_B2, C_G2, C_BT2};
    for (int seg = 0; seg < 11; ++seg)
        for (int i = threadIdx.x; i < ns[seg]; i += 256) {
            short v = f32 ? f2bs(((const float*)ps[seg])[i]) : ((const short*)ps[seg])[i];
            ((short*)canon)[os[seg] + i] = v;
        }
}

__global__ void k_repack_all(const void* __restrict__ emb_w, const void* __restrict__ lin_w,
                             const void* __restrict__ w1, const void* __restrict__ w2,
                             bf16* __restrict__ Wf, const int* __restrict__ flags) {
    const int starts[11] = {0, 16384, 24576, 32768, 40960, 73728, 106496,
                            139264, 172032, 204800, 237568};
    int idx = blockIdx.x * 256 + threadIdx.x;
    if (idx >= 237568) return;
    bool f32 = (flags[0] == 0);
    int seg = 0;
    while (idx >= starts[seg + 1]) ++seg;
    int local = idx - starts[seg];
    const void* base; long long eoff; int K, N;
    if (seg == 0)      { base = emb_w; eoff = 0;                          K = 128; N = 128; }
    else if (seg <= 3) { base = lin_w; eoff = (long long)(seg - 1) * 8192;  K = 64;  N = 128; }
    else if (seg <= 6) { base = w1;    eoff = (long long)(seg - 4) * 32768; K = 128; N = 256; }
    else               { base = w2;    eoff = (long long)(seg - 7) * 32768; K = 256; N = 128; }
    int j    = local & 7;
    int lane = (local >> 3) & 63;
    int rest = local >> 9;
    int NF   = N >> 4;
    int ks   = rest / NF;
    int nf   = rest - ks * NF;
    int k = ks * 32 + ((lane >> 4) << 3) + j;
    int n = (nf << 4) + (lane & 15);
    long long src = eoff + (long long)k * N + n;
    short v = f32 ? f2bs(((const float*)base)[src]) : ((const short*)base)[src];
    ((short*)Wf)[idx] = v;
}

// ================= sort by dst (counting sort) =================
__global__ void k_hist(const void* __restrict__ ei, int* __restrict__ deg,
                       const int* __restrict__ flags) {
    bool i64 = (flags[1] == 1);
    for (int e = blockIdx.x * 256 + threadIdx.x; e < NEDGES; e += gridDim.x * 256) {
        int d = i64 ? (int)((const long long*)ei)[NEDGES + e] : ((const int*)ei)[NEDGES + e];
        if ((unsigned)d < NNODES) atomicAdd(&deg[d], 1);
    }
}

__global__ __launch_bounds__(1024) void k_scan(const int* __restrict__ deg,
                                               int* __restrict__ rowptr) {
    __shared__ int part[1024];
    const int CH = 49;
    int t = threadIdx.x;
    int lo = t * CH, hi = lo + CH; if (hi > NNODES) hi = NNODES; if (lo > NNODES) lo = NNODES;
    int s = 0;
    for (int i = lo; i < hi; ++i) s += deg[i];
    part[t] = s;
    __syncthreads();
    for (int off = 1; off < 1024; off <<= 1) {
        int v = (t >= off) ? part[t - off] : 0;
        __syncthreads();
        part[t] += v;
        __syncthreads();
    }
    int run = (t == 0) ? 0 : part[t - 1];
    for (int i = lo; i < hi; ++i) { rowptr[i] = run; run += deg[i]; }
    if (t == 1023) rowptr[NNODES] = run;
}

__global__ void k_scatter(const void* __restrict__ ei, const int* __restrict__ rowptr,
                          int* __restrict__ cursor, int* __restrict__ srcs,
                          int* __restrict__ dsts, int* __restrict__ eids,
                          int* __restrict__ pos_of,
                          const int* __restrict__ flags) {
    bool i64 = (flags[1] == 1);
    for (int e = blockIdx.x * 256 + threadIdx.x; e < NEDGES; e += gridDim.x * 256) {
        int s, d;
        if (i64) {
            s = (int)((const long long*)ei)[e];
            d = (int)((const long long*)ei)[NEDGES + e];
        } else {
            s = ((const int*)ei)[e];
            d = ((const int*)ei)[NEDGES + e];
        }
        if ((unsigned)s >= NNODES || (unsigned)d >= NNODES) { pos_of[e] = -1; continue; }
        int pos = rowptr[d] + atomicAdd(&cursor[d], 1);
        srcs[pos] = s; dsts[pos] = d; eids[pos] = e; pos_of[e] = pos;
    }
}

// ---------- permute-gather of edge_attr, LINEAR coalesced read / random row write
__global__ void k_permEA3(const void* __restrict__ EA, const int* __restrict__ pos_of,
                          bf16* __restrict__ eaP, const int* __restrict__ flags) {
    bool f32 = (flags[0] == 0);
    int tid = blockIdx.x * 256 + threadIdx.x;
    int t = tid & 7;
    int r0 = (tid >> 3) * 4;
    if (r0 >= NEDGES) return;
    int p[4];
#pragma unroll
    for (int j = 0; j < 4; ++j) p[j] = pos_of[r0 + j];
    if (f32) {
        float4 a[4], b[4];
#pragma unroll
        for (int j = 0; j < 4; ++j) {
            const float4* q = reinterpret_cast<const float4*>(
                (const float*)EA + (size_t)(r0 + j) * 64 + t * 8);
            a[j] = q[0]; b[j] = q[1];
        }
#pragma unroll
        for (int j = 0; j < 4; ++j) {
            if (p[j] < 0) continue;
            bf16x8 r;
            r[0]=f2bs(a[j].x); r[1]=f2bs(a[j].y); r[2]=f2bs(a[j].z); r[3]=f2bs(a[j].w);
            r[4]=f2bs(b[j].x); r[5]=f2bs(b[j].y); r[6]=f2bs(b[j].z); r[7]=f2bs(b[j].w);
            *reinterpret_cast<bf16x8*>(eaP + (size_t)p[j] * 64 + t * 8) = r;
        }
    } else {
        bf16x8 a[4];
#pragma unroll
        for (int j = 0; j < 4; ++j)
            a[j] = *reinterpret_cast<const bf16x8*>(
                (const bf16*)EA + (size_t)(r0 + j) * 64 + t * 8);
#pragma unroll
        for (int j = 0; j < 4; ++j) {
            if (p[j] < 0) continue;
            *reinterpret_cast<bf16x8*>(eaP + (size_t)p[j] * 64 + t * 8) = a[j];
        }
    }
}

// ================= GEMM with fused bias + BN column stats =================
template<int K, int NF>
__global__ __launch_bounds__(256) void k_gemm(const void* __restrict__ A,
                                              const bf16* __restrict__ Wf,
                                              const bf16* __restrict__ bias,
                                              bf16* __restrict__ Y, int M,
                                              float* __restrict__ ssum,
                                              float* __restrict__ ssq,
                                              const int* __restrict__ flags, int flexA) {
    const int N = NF * 16;
    __shared__ float sred[2][4][N];
    bool f32 = flexA && (flags[0] == 0);
    int lane = threadIdx.x & 63, wave = threadIdx.x >> 6;
    int rowbase = blockIdx.x * 64 + wave * 16;
    int arow = rowbase + (lane & 15);
    bool aval = (arow < M);
    size_t abase = (size_t)arow * K + ((lane >> 4) << 3);
    f32x4 acc[NF] = {};
#pragma unroll
    for (int ks = 0; ks < K / 32; ++ks) {
        bf16x8 a = aval ? ld_a8(A, abase + ks * 32, f32) : zero8();
#pragma unroll
        for (int f = 0; f < NF; ++f) {
            bf16x8 b = ld_frag(Wf + (((ks * NF + f) * 64 + lane) << 3));
            acc[f] = __builtin_amdgcn_mfma_f32_16x16x32_bf16(a, b, acc[f], 0, 0, 0);
        }
    }
    int hi = lane >> 4, coll = lane & 15;
    int crow = rowbase + hi * 4;
#pragma unroll
    for (int f = 0; f < NF; ++f) {
        int col = f * 16 + coll;
        float bv = b2f(bias[col]);
        float s = 0.f, q = 0.f;
#pragma unroll
        for (int r = 0; r < 4; ++r) {
            int row = crow + r;
            if (row < M) {
                float v = acc[f][r] + bv;
                Y[(size_t)row * N + col] = __float2bfloat16(v);
                s += v; q += v * v;
            }
        }
        s += __shfl_xor(s, 16); s += __shfl_xor(s, 32);
        q += __shfl_xor(q, 16); q += __shfl_xor(q, 32);
        if (hi == 0) { sred[0][wave][col] = s; sred[1][wave][col] = q; }
    }
    __syncthreads();
    for (int t = threadIdx.x; t < N; t += 256) {
        float s = sred[0][0][t] + sred[0][1][t] + sred[0][2][t] + sred[0][3][t];
        float q = sred[1][0][t] + sred[1][1][t] + sred[1][2][t] + sred[1][3][t];
        atomicAdd(&ssum[t], s); atomicAdd(&ssq[t], q);
    }
}

// ======= GEMM with fused zin input (A = bf16((1+eps)h + agg)), K=128 =======
template<int NF>
__global__ __launch_bounds__(256) void k_gemm_zin(const bf16* __restrict__ h,
                                                  const float* __restrict__ agg,
                                                  const bf16* __restrict__ epsc, int layer,
                                                  const bf16* __restrict__ Wf,
                                                  const bf16* __restrict__ bias,
                                                  bf16* __restrict__ Y, int M,
                                                  float* __restrict__ ssum,
                                                  float* __restrict__ ssq) {
    const int K = 128, N = NF * 16;
    __shared__ float sred[2][4][N];
    float e1 = 1.f + b2f(epsc[layer]);
    int lane = threadIdx.x & 63, wave = threadIdx.x >> 6;
    int rowbase = blockIdx.x * 64 + wave * 16;
    int arow = rowbase + (lane & 15);
    bool aval = (arow < M);
    size_t abase = (size_t)arow * K + ((lane >> 4) << 3);
    f32x4 acc[NF] = {};
#pragma unroll
    for (int ks = 0; ks < 4; ++ks) {
        bf16x8 a;
        if (aval) {
            size_t off = abase + ks * 32;
            bf16x8 hv = ld_frag(h + off);
            float4 a0 = *reinterpret_cast<const float4*>(agg + off);
            float4 a1 = *reinterpret_cast<const float4*>(agg + off + 4);
            a[0] = f2bs(e1 * bs2f(hv[0]) + a0.x);
            a[1] = f2bs(e1 * bs2f(hv[1]) + a0.y);
            a[2] = f2bs(e1 * bs2f(hv[2]) + a0.z);
            a[3] = f2bs(e1 * bs2f(hv[3]) + a0.w);
            a[4] = f2bs(e1 * bs2f(hv[4]) + a1.x);
            a[5] = f2bs(e1 * bs2f(hv[5]) + a1.y);
            a[6] = f2bs(e1 * bs2f(hv[6]) + a1.z);
            a[7] = f2bs(e1 * bs2f(hv[7]) + a1.w);
        } else {
            a = zero8();
        }
#pragma unroll
        for (int f = 0; f < NF; ++f) {
            bf16x8 b = ld_frag(Wf + (((ks * NF + f) * 64 + lane) << 3));
            acc[f] = __builtin_amdgcn_mfma_f32_16x16x32_bf16(a, b, acc[f], 0, 0, 0);
        }
    }
    int hi = lane >> 4, coll = lane & 15;
    int crow = rowbase + hi * 4;
#pragma unroll
    for (int f = 0; f < NF; ++f) {
        int col = f * 16 + coll;
        float bv = b2f(bias[col]);
        float s = 0.f, q = 0.f;
#pragma unroll
        for (int r = 0; r < 4; ++r) {
            int row = crow + r;
            if (row < M) {
                float v = acc[f][r] + bv;
                Y[(size_t)row * N + col] = __float2bfloat16(v);
                s += v; q += v * v;
            }
        }
        s += __shfl_xor(s, 16); s += __shfl_xor(s, 32);
        q += __shfl_xor(q, 16); q += __shfl_xor(q, 32);
        if (hi == 0) { sred[0][wave][col] = s; sred[1][wave][col] = q; }
    }
    __syncthreads();
    for (int t = threadIdx.x; t < N; t += 256) {
        float s = sred[0][0][t] + sred[0][1][t] + sred[0][2][t] + sred[0][3][t];
        float q = sred[1][0][t] + sred[1][1][t] + sred[1][2][t] + sred[1][3][t];
        atomicAdd(&ssum[t], s); atomicAdd(&ssq[t], q);
    }
}

// ======= GEMM with fused BN+GELU on A (A = gelu(bn(y1raw))), K=256 =======
template<int NF>
__global__ __launch_bounds__(256) void k_gemm_bn(const bf16* __restrict__ A,
                                                 const float* __restrict__ ssumIn,
                                                 const float* __restrict__ ssqIn,
                                                 const bf16* __restrict__ gIn,
                                                 const bf16* __restrict__ btIn,
                                                 const bf16* __restrict__ Wf,
                                                 const bf16* __restrict__ bias,
                                                 bf16* __restrict__ Y, int M,
                                                 float* __restrict__ ssum,
                                                 float* __restrict__ ssq) {
    const int K = 256, N = NF * 16;
    __shared__ float sscale[K], sshift[K];
    __shared__ float sred[2][4][N];
    for (int c = threadIdx.x; c < K; c += 256) {
        const float invM = 1.f / (float)NNODES;
        float mean = ssumIn[c] * invM;
        float var  = ssqIn[c] * invM - mean * mean;
        float a = b2f(gIn[c]) * rsqrtf(fmaxf(var, 0.f) + 1e-5f);
        sscale[c] = a;
        sshift[c] = b2f(btIn[c]) - mean * a;
    }
    __syncthreads();
    int lane = threadIdx.x & 63, wave = threadIdx.x >> 6;
    int rowbase = blockIdx.x * 64 + wave * 16;
    int arow = rowbase + (lane & 15);
    bool aval = (arow < M);
    int koff = (lane >> 4) << 3;
    size_t abase = (size_t)arow * K + koff;
    f32x4 acc[NF] = {};
#pragma unroll
    for (int ks = 0; ks < 8; ++ks) {
        bf16x8 a;
        if (aval) {
            bf16x8 raw = ld_frag(A + abase + ks * 32);
            int c0 = ks * 32 + koff;
#pragma unroll
            for (int j = 0; j < 8; ++j) {
                float v = bs2f(raw[j]) * sscale[c0 + j] + sshift[c0 + j];
                a[j] = f2bs(gelu_ex(v));
            }
        } else {
            a = zero8();
        }
#pragma unroll
        for (int f = 0; f < NF; ++f) {
            bf16x8 b = ld_frag(Wf + (((ks * NF + f) * 64 + lane) << 3));
            acc[f] = __builtin_amdgcn_mfma_f32_16x16x32_bf16(a, b, acc[f], 0, 0, 0);
        }
    }
    int hi = lane >> 4, coll = lane & 15;
    int crow = rowbase + hi * 4;
#pragma unroll
    for (int f = 0; f < NF; ++f) {
        int col = f * 16 + coll;
        float bv = b2f(bias[col]);
        float s = 0.f, q = 0.f;
#pragma unroll
        for (int r = 0; r < 4; ++r) {
            int row = crow + r;
            if (row < M) {
                float v = acc[f][r] + bv;
                Y[(size_t)row * N + col] = __float2bfloat16(v);
                s += v; q += v * v;
            }
        }
        s += __shfl_xor(s, 16); s += __shfl_xor(s, 32);
        q += __shfl_xor(q, 16); q += __shfl_xor(q, 32);
        if (hi == 0) { sred[0][wave][col] = s; sred[1][wave][col] = q; }
    }
    __syncthreads();
    for (int t = threadIdx.x; t < N; t += 256) {
        float s = sred[0][0][t] + sred[0][1][t] + sred[0][2][t] + sred[0][3][t];
        float q = sred[1][0][t] + sred[1][1][t] + sred[1][2][t] + sred[1][3][t];
        atomicAdd(&ssum[t], s); atomicAdd(&ssq[t], q);
    }
}

// ===== k_edge6c: CSR node-parallel, low-VGPR + next-chunk register prefetch =====
// (proven: A/B on layer 1 round 17; adopted on all layers)
__global__ __launch_bounds__(64, 8) void k_edge6c(const bf16* __restrict__ eaP,
                                                  const void* __restrict__ EA,
                                                  const int* __restrict__ eids,
                                                  const bf16* __restrict__ Wf,
                                                  const bf16* __restrict__ bias,
                                                  const int* __restrict__ srcs,
                                                  const int* __restrict__ rowptr,
                                                  const bf16* __restrict__ h,
                                                  float* __restrict__ agg,
                                                  const int* __restrict__ flags) {
    __shared__ short sm[16 * 132];
    __shared__ unsigned hbuf[16 * 64];
    bool f32 = (flags[0] == 0);
    int lane = threadIdx.x & 63;
    int d = blockIdx.x;
    int start = rowptr[d], end = rowptr[d + 1];
    int koff = (lane >> 4) << 3;
    int l2 = lane * 2;
    int hi = lane >> 4, coll = lane & 15;
    int rbase = hi * 4;
    float bx = b2f(bias[l2]), by = b2f(bias[l2 + 1]);
    float rx = 0.f, ry = 0.f;
    // prologue: load chunk 0 operands
    int ok_l = 0, sc_l = 0;
    bf16x8 a0 = zero8(), a1 = zero8();
    if (start < end) {
        int eidx = start + (lane & 15);
        ok_l = (eidx < end) ? 1 : 0;
        sc_l = ok_l ? srcs[eidx] : 0;
        if (eaP) {
            const bf16* ap = eaP + (size_t)eidx * 64 + koff;
            if (ok_l) { a0 = ld_frag(ap); a1 = ld_frag(ap + 32); }
        } else {
            size_t abase = ok_l ? ((size_t)eids[eidx] * 64 + koff) : 0;
            if (ok_l) { a0 = ld_a8(EA, abase, f32); a1 = ld_a8(EA, abase + 32, f32); }
        }
    }
    bool first = true;
    for (int c = start; c < end; c += 16) {
        if (!first) __syncthreads();
        first = false;
        {
            f32x4 acc[4] = {};
#pragma unroll
            for (int j = 0; j < 4; ++j) {
                acc[j] = __builtin_amdgcn_mfma_f32_16x16x32_bf16(
                    a0, ld_frag(Wf + (((0 * 8 + j) * 64 + lane) << 3)), acc[j], 0, 0, 0);
                acc[j] = __builtin_amdgcn_mfma_f32_16x16x32_bf16(
                    a1, ld_frag(Wf + (((1 * 8 + j) * 64 + lane) << 3)), acc[j], 0, 0, 0);
            }
#pragma unroll
            for (int j = 0; j < 4; ++j)
#pragma unroll
                for (int r = 0; r < 4; ++r)
                    sm[(rbase + r) * 132 + j * 16 + coll] = f2bs(acc[j][r]);
        }
        {
            f32x4 acc[4] = {};
#pragma unroll
            for (int j = 0; j < 4; ++j) {
                acc[j] = __builtin_amdgcn_mfma_f32_16x16x32_bf16(
                    a0, ld_frag(Wf + (((0 * 8 + 4 + j) * 64 + lane) << 3)), acc[j], 0, 0, 0);
                acc[j] = __builtin_amdgcn_mfma_f32_16x16x32_bf16(
                    a1, ld_frag(Wf + (((1 * 8 + 4 + j) * 64 + lane) << 3)), acc[j], 0, 0, 0);
            }
#pragma unroll
            for (int j = 0; j < 4; ++j)
#pragma unroll
                for (int r = 0; r < 4; ++r)
                    sm[(rbase + r) * 132 + (4 + j) * 16 + coll] = f2bs(acc[j][r]);
        }
#pragma unroll
        for (int e = 0; e < 16; ++e) {
            int s = __shfl(sc_l, e);
            hbuf[e * 64 + lane] = *reinterpret_cast<const unsigned*>(
                reinterpret_cast<const unsigned short*>(h) + (size_t)s * 128 + l2);
        }
        // ---- prefetch NEXT chunk's operands (registers only; overlaps reduce)
        int cn = c + 16;
        if (cn < end) {
            int eidx = cn + (lane & 15);
            ok_l = (eidx < end) ? 1 : 0;
            sc_l = ok_l ? srcs[eidx] : 0;
            if (eaP) {
                const bf16* ap = eaP + (size_t)eidx * 64 + koff;
                a0 = ok_l ? ld_frag(ap)      : zero8();
                a1 = ok_l ? ld_frag(ap + 32) : zero8();
            } else {
                size_t abase = ok_l ? ((size_t)eids[eidx] * 64 + koff) : 0;
                a0 = ok_l ? ld_a8(EA, abase, f32)      : zero8();
                a1 = ok_l ? ld_a8(EA, abase + 32, f32) : zero8();
            }
        }
        __syncthreads();
        int lim = end - c; if (lim > 16) lim = 16;
        for (int e = 0; e < lim; ++e) {
            unsigned mu = *reinterpret_cast<const unsigned*>(&sm[e * 132 + l2]);
            unsigned hu = hbuf[e * 64 + lane];
            float vx = u2f_lo(mu) + u2f_lo(hu) + bx;
            float vy = u2f_hi(mu) + u2f_hi(hu) + by;
            rx += fmaxf(vx, 0.f); ry += fmaxf(vy, 0.f);
        }
    }
    agg[(size_t)d * 128 + l2]     = rx;
    agg[(size_t)d * 128 + l2 + 1] = ry;
}

// ---------- legacy unsorted edge kernel (tier C fallback)
__global__ __launch_bounds__(256) void k_edge(const void* __restrict__ EA,
                                              const bf16* __restrict__ Wf,
                                              const bf16* __restrict__ bias,
                                              const void* __restrict__ ei,
                                              const bf16* __restrict__ h,
                                              float* __restrict__ agg,
                                              const int* __restrict__ flags) {
    bool f32 = (flags[0] == 0);
    bool i64 = (flags[1] == 1);
    const int K = 64, NF = 8;
    int lane = threadIdx.x & 63, wave = threadIdx.x >> 6;
    int rowbase = blockIdx.x * 64 + wave * 16;
    int colbase = blockIdx.y * 64;
    int arow = rowbase + (lane & 15);
    size_t abase = (size_t)arow * K + ((lane >> 4) << 3);
    f32x4 acc[4] = {};
#pragma unroll
    for (int ks = 0; ks < 2; ++ks) {
        bf16x8 a = ld_a8(EA, abase + ks * 32, f32);
#pragma unroll
        for (int f = 0; f < 4; ++f) {
            bf16x8 b = ld_frag(Wf + (((ks * NF + colbase / 16 + f) * 64 + lane) << 3));
            acc[f] = __builtin_amdgcn_mfma_f32_16x16x32_bf16(a, b, acc[f], 0, 0, 0);
        }
    }
    int erow = rowbase + ((lane >> 4) << 2);
    int coll = lane & 15;
    float bv[4];
#pragma unroll
    for (int f = 0; f < 4; ++f) bv[f] = b2f(bias[colbase + f * 16 + coll]);
#pragma unroll
    for (int r = 0; r < 4; ++r) {
        int e = erow + r;
        int s, d;
        if (i64) {
            s = (int)((const long long*)ei)[e];
            d = (int)((const long long*)ei)[NEDGES + e];
        } else {
            s = ((const int*)ei)[e];
            d = ((const int*)ei)[NEDGES + e];
        }
        if ((unsigned)s >= NNODES || (unsigned)d >= NNODES) continue;
        const bf16* hp = h + (size_t)s * HIDDEN;
        float* gp = agg + (size_t)d * HIDDEN;
#pragma unroll
        for (int f = 0; f < 4; ++f) {
            int col = colbase + f * 16 + coll;
            float v = acc[f][r] + bv[f] + b2f(hp[col]);
            if (v > 0.f) atomicAdd(gp + col, v);
        }
    }
}

// ---------- fused BN-finalize + normalize + exact GELU (x4) + optional agg-zero tail
template<int N>
__global__ void k_bngelu4(const bf16* __restrict__ y, const float* __restrict__ ssum,
                          const float* __restrict__ ssq, const bf16* __restrict__ g,
                          const bf16* __restrict__ beta, bf16* __restrict__ z,
                          void* __restrict__ out_base, int slice,
                          const int* __restrict__ flags,
                          float* __restrict__ aggz, int aggn4) {
    __shared__ float sscale[N], sshift[N];
    for (int c = threadIdx.x; c < N; c += 256) {
        const float invM = 1.f / (float)NNODES;
        float mean = ssum[c] * invM;
        float var  = ssq[c] * invM - mean * mean;
        float a = b2f(g[c]) * rsqrtf(fmaxf(var, 0.f) + 1e-5f);
        sscale[c] = a;
        sshift[c] = b2f(beta[c]) - mean * a;
    }
    __syncthreads();
    bool outb = (flags[0] == 1);
    const int total4 = NNODES * N / 4;
    for (int i4 = blockIdx.x * 256 + threadIdx.x; i4 < total4; i4 += gridDim.x * 256) {
        int i = i4 * 4;
        int col = i & (N - 1);
        ushort4 yv = ((const ushort4*)y)[i4];
        float g0 = gelu_ex(u2f_lo(yv.x) * sscale[col]     + sshift[col]);
        float g1 = gelu_ex(u2f_lo(yv.y) * sscale[col + 1] + sshift[col + 1]);
        float g2 = gelu_ex(u2f_lo(yv.z) * sscale[col + 2] + sshift[col + 2]);
        float g3 = gelu_ex(u2f_lo(yv.w) * sscale[col + 3] + sshift[col + 3]);
        ushort4 zv;
        zv.x = (unsigned short)f2bs(g0); zv.y = (unsigned short)f2bs(g1);
        zv.z = (unsigned short)f2bs(g2); zv.w = (unsigned short)f2bs(g3);
        ((ushort4*)z)[i4] = zv;
        if (slice >= 0) {
            int row = i / N;
            size_t ob = (size_t)row * 512 + (size_t)slice * 128 + col;
            if (outb) {
                *reinterpret_cast<ushort4*>((unsigned short*)out_base + ob) = zv;
            } else {
                float4 gv = {g0, g1, g2, g3};
                *reinterpret_cast<float4*>((float*)out_base + ob) = gv;
            }
        }
    }
    if (aggz) {
        float4 zzz = {0.f, 0.f, 0.f, 0.f};
        for (int i4 = blockIdx.x * 256 + threadIdx.x; i4 < aggn4; i4 += gridDim.x * 256)
            ((float4*)aggz)[i4] = zzz;
    }
}

extern "C" void kernel_launch(void* const* d_in, const int* in_sizes, int n_in,
                              void* d_out, int out_size, void* d_ws, size_t ws_size,
                              hipStream_t stream) {
    const void* x      = d_in[0];
    const void* ei     = d_in[1];
    const void* ea     = d_in[2];
    const void* emb_w  = d_in[3];
    const void* emb_b  = d_in[4];
    const void* emb_g  = d_in[5];
    const void* emb_bt = d_in[6];
    const void* eps    = d_in[7];
    const void* lin_w  = d_in[8];
    const void* lin_b  = d_in[9];
    const void* w1     = d_in[10];
    const void* b1     = d_in[11];
    const void* g1     = d_in[12];
    const void* bt1    = d_in[13];
    const void* w2     = d_in[14];
    const void* b2     = d_in[15];
    const void* g2     = d_in[16];
    const void* bt2    = d_in[17];

    char* ws = (char*)d_ws;
    int*   flags  = (int*)ws;
    float* stats  = (float*)(ws + 1024);
    bf16*  canon  = (bf16*)(ws + 16384);
    bf16*  wf0    = (bf16*)(ws + 32768);
    bf16*  lin_wf = wf0 + 16384;
    bf16*  w1f    = wf0 + 40960;
    bf16*  w2f    = wf0 + 139264;
    bf16*  bufH   = (bf16*)(ws + 524288);       // [50000,128] bf16 (y0 / h)
    bf16*  bufA   = (bf16*)(ws + 13324288);     // [50000,128] bf16 (y2)
    char*  bufC   = (ws + 26124288);            // 25.6 MB (agg fp32 | y1 bf16)
    float* aggf   = (float*)bufC;
    bf16*  y1     = (bf16*)bufC;
    const size_t SB = 51724288;
    int*  rowptr  = (int*)(ws + SB);
    int*  cursorA = (int*)(ws + SB + 200704);
    int*  srcs    = (int*)(ws + SB + 401408);
    int*  dsts    = (int*)(ws + SB + 3601408);
    int*  eids    = (int*)(ws + SB + 6801408);
    bf16* eaP     = (bf16*)(ws + SB + 10001408);
    int*  cursorB = (int*)bufA;                       // dead region during sort phase
    int*  pos_of  = (int*)(ws + 13324288 + 1048576);  // bufA+1MB, dead during sort phase
    const unsigned long long TIERA_NEED = SB + 10001408ull + 102400000ull;
    const unsigned long long TIERB_NEED = SB + 10001408ull;
    bool tierA = ws_size >= TIERA_NEED;
    bool tierB = !tierA && ws_size >= TIERB_NEED;
    bool sorted = tierA || tierB;
    const int AGGN4 = NNODES * HIDDEN / 4;

    k_init<<<256, 256, 0, stream>>>(stats, cursorA, cursorB, sorted ? 1 : 0);
    k_detect_cvt<<<1, 256, 0, stream>>>((const unsigned*)emb_g, (const unsigned*)ei, flags,
                                        emb_b, emb_g, emb_bt, eps, lin_b, b1, g1, bt1,
                                        b2, g2, bt2, canon);
    k_repack_all<<<928, 256, 0, stream>>>(emb_w, lin_w, w1, w2, wf0, flags);

    if (sorted) {
        k_hist<<<1024, 256, 0, stream>>>(ei, cursorA, flags);
        k_scan<<<1, 1024, 0, stream>>>(cursorA, rowptr);
        k_scatter<<<1024, 256, 0, stream>>>(ei, rowptr, cursorB, srcs, dsts, eids,
                                            pos_of, flags);
        if (tierA) k_permEA3<<<6250, 256, 0, stream>>>(ea, pos_of, eaP, flags);
    }

    // ---- node embed (stats slot 0); tier-C needs agg pre-zeroed via bngelu tail
    float* aggz0 = sorted ? (float*)nullptr : aggf;
    k_gemm<128, 8><<<782, 256, 0, stream>>>(x, wf0, canon + C_EMB_B, bufH, NNODES,
                                            stats, stats + 256, flags, 1);
    k_bngelu4<128><<<2048, 256, 0, stream>>>(bufH, stats, stats + 256,
                                             canon + C_EMB_G, canon + C_EMB_BT,
                                             bufH, d_out, 0, flags, aggz0, AGGN4);

    for (int i = 0; i < 3; ++i) {
        float* s1 = stats + (size_t)(1 + 2 * i) * 512;
        float* s2 = stats + (size_t)(2 + 2 * i) * 512;
        if (sorted) {
            const bf16* pA = tierA ? eaP : (const bf16*)nullptr;
            const void* pE = tierA ? (const void*)nullptr : ea;
            const int*  pI = tierA ? (const int*)nullptr : eids;
            k_edge6c<<<NNODES, 64, 0, stream>>>(pA, pE, pI,
                                                lin_wf + i * 8192,
                                                canon + C_LIN_B + i * 128,
                                                srcs, rowptr, bufH, aggf, flags);
        } else {
            k_edge<<<dim3(12500, 2), 256, 0, stream>>>(ea, lin_wf + i * 8192,
                                                       canon + C_LIN_B + i * 128, ei,
                                                       bufH, aggf, flags);
        }
        // MLP layer 1 with fused zin (stats slot 1+2i); y1 = raw pre-BN output
        k_gemm_zin<16><<<782, 256, 0, stream>>>(bufH, aggf, canon + C_EPS, i,
                                                w1f + i * 32768, canon + C_B1 + i * 256,
                                                y1, NNODES, s1, s1 + 256);
        // MLP layer 2 with consumer-fused BN+GELU on y1 (stats slot 2+2i)
        k_gemm_bn<8><<<782, 256, 0, stream>>>(y1, s1, s1 + 256, canon + C_G1 + i * 256,
                                              canon + C_BT1 + i * 256,
                                              w2f + i * 32768, canon + C_B2 + i * 128,
                                              bufA, NNODES, s2, s2 + 256);
        // slice bngelu; tier-C zero-tail for next layer's atomics (sorted path: none)
        float* aggz = (!sorted && i < 2) ? aggf : (float*)nullptr;
        k_bngelu4<128><<<2048, 256, 0, stream>>>(bufA, s2, s2 + 256, canon + C_G2 + i * 128,
                                                 canon + C_BT2 + i * 128, bufH, d_out,
                                                 i + 1, flags, aggz, AGGN4);
    }
}